// Round 1
// baseline (1786.582 us; speedup 1.0000x reference)
//
#include <hip/hip_runtime.h>
#include <stdint.h>

// ---------------------------------------------------------------------------
// Shapes (fixed by the reference): V=32000, D=512, H=4, L=4, B=4, S=512
// Output: logits (4,1,32000) fp32.
// Strategy:
//  - bf16 MFMA for the big vocab GEMMs (error damped by softmax over 32000).
//  - split-bf16 (hi/lo, 3-term) MFMA for Q/K/krn (near-fp32 accuracy).
//  - fp32 shadow path for f_k[:,511,:] (the only row that reaches the output;
//    final LN amplifies by ~316 since var(f_k_last) << eps).
//  - layer 0: softmax(0) is uniform -> ex_wte = colmean(wte) exactly.
// ---------------------------------------------------------------------------

typedef __attribute__((ext_vector_type(8))) short s16x8;
typedef __attribute__((ext_vector_type(4))) short s16x4;
typedef __attribute__((ext_vector_type(4))) float f32x4;

__device__ __forceinline__ short f2bf(float f) {
  unsigned u = __float_as_uint(f);
  unsigned r = (u + 0x7FFFu + ((u >> 16) & 1u)) >> 16;  // RNE
  return (short)r;
}
__device__ __forceinline__ float bf2f(short u) {
  unsigned v = ((unsigned)(unsigned short)u) << 16;
  return __uint_as_float(v);
}

// ---------------------------------------------------------------------------
// Generic NT GEMM: C[m,n] (+)= sum_k A[m,k] * B[n,k], A (MxK), B (NxK) bf16.
// 128x128 tile, BK=32, 256 threads (4 waves, each 64x64 via 4x4 mfma 16x16x32).
// z-dim: zq=z/zdiv, zr=z%zdiv. Batch strides in *elements*. k0 = zr*k0_mul
// (split-K offset applied to both A and B).
// EPI: 0 = store bf16; 1 = atomicAdd fp32; 2 = store bf16 scaled by 1/(1+row).
// ---------------------------------------------------------------------------
template <int EPI>
__global__ void __launch_bounds__(256) gemm_nt(
    const short* __restrict__ Ag, const short* __restrict__ Bg,
    void* __restrict__ Cg, int lda, int ldb, int ldc, int klen, int k0_mul,
    int zdiv, long sAq, long sAr, long sBq, long sBr, long sCq, long sCr) {
  const int tid = threadIdx.x;
  const int z = blockIdx.z;
  const int zq = z / zdiv, zr = z % zdiv;
  const short* A = Ag + zq * sAq + zr * sAr + (long)zr * k0_mul;
  const short* B = Bg + zq * sBq + zr * sBr + (long)zr * k0_mul;
  const long cOff = zq * sCq + zr * sCr;

  __shared__ __align__(16) short As[128 * 32];
  __shared__ __align__(16) short Bs[128 * 32];

  const long m0 = (long)blockIdx.x * 128;
  const long n0 = (long)blockIdx.y * 128;

  const int wave = tid >> 6, lane = tid & 63;
  const int wm = (wave >> 1) * 64, wn = (wave & 1) * 64;
  const int mlan = lane & 15, kg = lane >> 4;

  f32x4 acc[4][4] = {};

  const int srow = tid >> 2;          // 0..63
  const int skoff = (tid & 3) * 8;    // 0,8,16,24 (bf16 elems)

  const int nk = klen >> 5;
  for (int kt = 0; kt < nk; ++kt) {
    const long kb = (long)kt * 32;
    s16x8 a0 = *(const s16x8*)(A + (m0 + srow) * (long)lda + kb + skoff);
    s16x8 a1 = *(const s16x8*)(A + (m0 + srow + 64) * (long)lda + kb + skoff);
    s16x8 b0 = *(const s16x8*)(B + (n0 + srow) * (long)ldb + kb + skoff);
    s16x8 b1 = *(const s16x8*)(B + (n0 + srow + 64) * (long)ldb + kb + skoff);
    __syncthreads();
    *(s16x8*)(As + srow * 32 + skoff) = a0;
    *(s16x8*)(As + (srow + 64) * 32 + skoff) = a1;
    *(s16x8*)(Bs + srow * 32 + skoff) = b0;
    *(s16x8*)(Bs + (srow + 64) * 32 + skoff) = b1;
    __syncthreads();
    s16x8 af[4], bfr[4];
#pragma unroll
    for (int i = 0; i < 4; ++i) {
      af[i] = *(const s16x8*)(As + (wm + i * 16 + mlan) * 32 + kg * 8);
      bfr[i] = *(const s16x8*)(Bs + (wn + i * 16 + mlan) * 32 + kg * 8);
    }
#pragma unroll
    for (int mi = 0; mi < 4; ++mi)
#pragma unroll
      for (int ni = 0; ni < 4; ++ni)
        acc[mi][ni] = __builtin_amdgcn_mfma_f32_16x16x32_bf16(
            af[mi], bfr[ni], acc[mi][ni], 0, 0, 0);
  }

  const int rq = (lane >> 4) * 4;
#pragma unroll
  for (int mi = 0; mi < 4; ++mi) {
#pragma unroll
    for (int ni = 0; ni < 4; ++ni) {
#pragma unroll
      for (int r = 0; r < 4; ++r) {
        long row = m0 + wm + mi * 16 + rq + r;   // M index
        long col = n0 + wn + ni * 16 + mlan;     // N index
        float v = acc[mi][ni][r];
        if (EPI == 1) {
          atomicAdd((float*)Cg + cOff + row * (long)ldc + col, v);
        } else {
          if (EPI == 2) v *= 1.0f / (1.0f + (float)row);
          *((short*)Cg + cOff + row * (long)ldc + col) = f2bf(v);
        }
      }
    }
  }
}

// ---------------------------------------------------------------------------
// LayerNorm of 512-wide rows. mode 0: gather wte[x[r]] -> o32 (e).
// mode 1: src rows -> hi/lo bf16 (p). mode 2: src rows -> o32 (final LN).
// ---------------------------------------------------------------------------
__global__ void __launch_bounds__(256) ln_rows(
    const float* __restrict__ src, const int* __restrict__ tok,
    const float* __restrict__ wte, const float* __restrict__ g,
    float* __restrict__ o32, short* __restrict__ ohi, short* __restrict__ olo,
    int mode) {
  int r = blockIdx.x, tid = threadIdx.x;
  const float* in;
  if (mode == 0)
    in = wte + (long)tok[r] * 512;
  else
    in = src + (long)r * 512;
  int d = tid * 2;
  float2 v = *(const float2*)(in + d);
  float s1 = v.x + v.y;
  float s2 = v.x * v.x + v.y * v.y;
  __shared__ float red[20];
  for (int o = 32; o > 0; o >>= 1) {
    s1 += __shfl_down(s1, o);
    s2 += __shfl_down(s2, o);
  }
  int wave = tid >> 6, lane = tid & 63;
  if (lane == 0) { red[wave] = s1; red[wave + 8] = s2; }
  __syncthreads();
  if (tid == 0) {
    float a = red[0] + red[1] + red[2] + red[3];
    float b = red[8] + red[9] + red[10] + red[11];
    float mean = a * (1.f / 512.f);
    float var = b * (1.f / 512.f) - mean * mean;
    red[16] = mean;
    red[17] = 1.0f / sqrtf(var + 1e-5f);
  }
  __syncthreads();
  float mean = red[16], rs = red[17];
  float2 gg = *(const float2*)(g + d);
  float y0 = (v.x - mean) * rs * gg.x;
  float y1 = (v.y - mean) * rs * gg.y;
  long o = (long)r * 512 + d;
  if (o32) { o32[o] = y0; o32[o + 1] = y1; }
  if (ohi) {
    short h0 = f2bf(y0), h1 = f2bf(y1);
    ohi[o] = h0; ohi[o + 1] = h1;
    if (olo) {
      olo[o] = f2bf(y0 - bf2f(h0));
      olo[o + 1] = f2bf(y1 - bf2f(h1));
    }
  }
}

// In-place softmax over each row of S (2048 rows x 32000 bf16).
__global__ void __launch_bounds__(256) softmax_vocab(short* __restrict__ S) {
  const int NV = 32000 / 8;
  long base = (long)blockIdx.x * 32000;
  int tid = threadIdx.x;
  float m = -3.0e38f, l = 0.f;
  for (int i = tid; i < NV; i += 256) {
    s16x8 v = *(const s16x8*)(S + base + (long)i * 8);
    float x[8];
#pragma unroll
    for (int j = 0; j < 8; j++) x[j] = bf2f(v[j]);
    float mv = x[0];
#pragma unroll
    for (int j = 1; j < 8; j++) mv = fmaxf(mv, x[j]);
    if (mv > m) { l *= __expf(m - mv); m = mv; }
#pragma unroll
    for (int j = 0; j < 8; j++) l += __expf(x[j] - m);
  }
  for (int o = 32; o > 0; o >>= 1) {
    float m2 = __shfl_down(m, o), l2 = __shfl_down(l, o);
    float mn = fmaxf(m, m2);
    l = l * __expf(m - mn) + l2 * __expf(m2 - mn);
    m = mn;
  }
  __shared__ float sm[8], sl[8];
  int wave = tid >> 6, lane = tid & 63;
  if (lane == 0) { sm[wave] = m; sl[wave] = l; }
  __syncthreads();
  if (tid == 0) {
    float M = sm[0], L = sl[0];
    for (int w = 1; w < 4; w++) {
      float mn = fmaxf(M, sm[w]);
      L = L * __expf(M - mn) + sl[w] * __expf(sm[w] - mn);
      M = mn;
    }
    sm[4] = M; sl[4] = 1.0f / L;
  }
  __syncthreads();
  float M = sm[4], IL = sl[4];
  for (int i = tid; i < NV; i += 256) {
    s16x8 v = *(const s16x8*)(S + base + (long)i * 8);
    s16x8 o;
#pragma unroll
    for (int j = 0; j < 8; j++) o[j] = f2bf(__expf(bf2f(v[j]) - M) * IL);
    *(s16x8*)(S + base + (long)i * 8) = o;
  }
}

// Attention softmax: raw (H,S,S) fp32 -> scale, clip(+-10), causal, softmax.
__global__ void __launch_bounds__(256) softmax_krn_k(
    const float* __restrict__ raw, float* __restrict__ k32,
    short* __restrict__ k16) {
  int bx = blockIdx.x;
  int h = bx >> 9, s = bx & 511;
  long base = ((long)h * 512 + s) * 512;
  int tid = threadIdx.x;
  const float scale = 0.04419417382415922f;  // 1/sqrt(512)
  float e0 = 0.f, e1 = 0.f, l = 0.f;
  int t0 = tid, t1 = tid + 256;
  if (t0 <= s) {
    float v = raw[base + t0] * scale;
    v = fminf(fmaxf(v, -10.f), 10.f);
    e0 = __expf(v); l += e0;
  }
  if (t1 <= s) {
    float v = raw[base + t1] * scale;
    v = fminf(fmaxf(v, -10.f), 10.f);
    e1 = __expf(v); l += e1;
  }
  for (int o = 32; o > 0; o >>= 1) l += __shfl_down(l, o);
  __shared__ float red[10];
  int wave = tid >> 6, lane = tid & 63;
  if (lane == 0) red[wave] = l;
  __syncthreads();
  if (tid == 0) red[8] = 1.0f / (red[0] + red[1] + red[2] + red[3]);
  __syncthreads();
  float inv = red[8];
  k32[base + t0] = e0 * inv;
  k16[base + t0] = f2bf(e0 * inv);
  k32[base + t1] = e1 * inv;
  k16[base + t1] = f2bf(e1 * inv);
}

// Transpose+cast: in (RxC) f32 -> out (CxR) bf16 hi (and optional lo).
__global__ void __launch_bounds__(256) transpose_cast(
    const float* __restrict__ in, short* __restrict__ hi,
    short* __restrict__ lo, int R, int C) {
  long bo = (long)blockIdx.z * R * C;
  const float* inp = in + bo;
  short* ho = hi + bo;
  short* lop = lo ? lo + bo : nullptr;
  int c0 = blockIdx.x * 64, r0 = blockIdx.y * 64;
  __shared__ float tl[64][65];
  int tid = threadIdx.x;
  for (int it = 0; it < 16; ++it) {
    int idx = it * 256 + tid;
    int rr = idx >> 6, cc = idx & 63;
    tl[rr][cc] = inp[(long)(r0 + rr) * C + (c0 + cc)];
  }
  __syncthreads();
  for (int it = 0; it < 16; ++it) {
    int idx = it * 256 + tid;
    int rr = idx >> 6, cc = idx & 63;
    float v = tl[cc][rr];
    long o = (long)(c0 + rr) * R + (r0 + cc);
    short hh = f2bf(v);
    ho[o] = hh;
    if (lop) lop[o] = f2bf(v - bf2f(hh));
  }
}

// Elementwise f32 -> bf16 hi (and optional lo residual). n4 = n/4.
__global__ void __launch_bounds__(256) cast_hilo(
    const float* __restrict__ in, short* __restrict__ hi,
    short* __restrict__ lo, long n4) {
  long i = (long)blockIdx.x * 256 + threadIdx.x;
  if (i >= n4) return;
  float4 v = ((const float4*)in)[i];
  s16x4 h;
  h[0] = f2bf(v.x); h[1] = f2bf(v.y); h[2] = f2bf(v.z); h[3] = f2bf(v.w);
  *(s16x4*)(hi + i * 4) = h;
  if (lo) {
    s16x4 L;
    L[0] = f2bf(v.x - bf2f(h[0])); L[1] = f2bf(v.y - bf2f(h[1]));
    L[2] = f2bf(v.z - bf2f(h[2])); L[3] = f2bf(v.w - bf2f(h[3]));
    *(s16x4*)(lo + i * 4) = L;
  }
}

// Column mean of wte (32000x512) -> cm[512]. Grid 125, 256 rows per block.
__global__ void __launch_bounds__(256) colmean_k(const float* __restrict__ wte,
                                                 float* __restrict__ cm) {
  int d = threadIdx.x * 2;
  long r0 = (long)blockIdx.x * 256;
  float a0 = 0.f, a1 = 0.f;
  for (int r = 0; r < 256; r++) {
    float2 v = *(const float2*)(wte + (r0 + r) * 512 + d);
    a0 += v.x; a1 += v.y;
  }
  atomicAdd(&cm[d], a0 * (1.f / 32000.f));
  atomicAdd(&cm[d + 1], a1 * (1.f / 32000.f));
}

// Vm = e - ex_wte (or colmean at layer 0): writes vm32 and vmT16 (b,e,t).
__global__ void __launch_bounds__(256) vm_k(
    const float* __restrict__ e32, const float* __restrict__ exw,
    const float* __restrict__ cm, int useCm, float* __restrict__ vm32,
    short* __restrict__ vmT) {
  int b = blockIdx.z, t0 = blockIdx.y * 64, e0 = blockIdx.x * 64;
  __shared__ short tl[64][72];
  int tid = threadIdx.x;
  long base = ((long)b * 512 + t0) * 512 + e0;
  for (int it = 0; it < 16; ++it) {
    int idx = it * 256 + tid;
    int rr = idx >> 6, cc = idx & 63;
    long o = base + (long)rr * 512 + cc;
    float v = e32[o] - (useCm ? cm[e0 + cc] : exw[o]);
    vm32[o] = v;
    tl[rr][cc] = f2bf(v);
  }
  __syncthreads();
  for (int it = 0; it < 16; ++it) {
    int idx = it * 256 + tid;
    int rr = idx >> 6, cc = idx & 63;
    vmT[((long)b * 512 + (e0 + rr)) * 512 + (t0 + cc)] = tl[cc][rr];
  }
}

// Shadow fp32 path, step 1: delta_last[b, h*512+e] = coef[511]*sum_t krn[h,511,t]*Vm[b,t,e]
__global__ void __launch_bounds__(256) dlast_k(
    const float* __restrict__ krn32, const float* __restrict__ vm32,
    float* __restrict__ dl) {
  int b = blockIdx.x >> 2, h = blockIdx.x & 3;
  int tid = threadIdx.x;
  __shared__ float w[512];
  long kb = ((long)h * 512 + 511) * 512;
  w[tid] = krn32[kb + tid];
  w[tid + 256] = krn32[kb + tid + 256];
  __syncthreads();
  float a0 = 0.f, a1 = 0.f;
  int e0 = tid, e1 = tid + 256;
  const float* vb = vm32 + (long)b * 512 * 512;
  for (int t = 0; t < 512; t++) {
    float wt = w[t];
    a0 += wt * vb[(long)t * 512 + e0];
    a1 += wt * vb[(long)t * 512 + e1];
  }
  dl[(long)b * 2048 + h * 512 + e0] = a0 * (1.f / 512.f);
  dl[(long)b * 2048 + h * 512 + e1] = a1 * (1.f / 512.f);
}

// Shadow step 2: f_last[b,d] += sum_k dl[b,k] * W_o[d,k]   (fp32)
__global__ void __launch_bounds__(256) flast_k(
    const float* __restrict__ dl, const float* __restrict__ Wo,
    float* __restrict__ fl) {
  int b = blockIdx.y, d = blockIdx.x * 256 + threadIdx.x;
  __shared__ float ds_[2048];
  for (int i = threadIdx.x; i < 2048; i += 256) ds_[i] = dl[(long)b * 2048 + i];
  __syncthreads();
  const float* wr = Wo + (long)d * 2048;
  float acc = 0.f;
  for (int k = 0; k < 2048; k += 4) {
    float4 wv = *(const float4*)(wr + k);
    acc += ds_[k] * wv.x + ds_[k + 1] * wv.y + ds_[k + 2] * wv.z +
           ds_[k + 3] * wv.w;
  }
  fl[(long)b * 512 + d] += acc;
}

// logits[b,v] = dot(outln[b,:], wte[v,:]) fp32. One wave handles 16 rows.
__global__ void __launch_bounds__(256) logits_k(
    const float* __restrict__ outln, const float* __restrict__ wte,
    float* __restrict__ out) {
  int tid = threadIdx.x, wave = tid >> 6, lane = tid & 63;
  float o[4][8];
#pragma unroll
  for (int b = 0; b < 4; b++) {
    float4 q0 = *(const float4*)(outln + b * 512 + lane * 8);
    float4 q1 = *(const float4*)(outln + b * 512 + lane * 8 + 4);
    o[b][0] = q0.x; o[b][1] = q0.y; o[b][2] = q0.z; o[b][3] = q0.w;
    o[b][4] = q1.x; o[b][5] = q1.y; o[b][6] = q1.z; o[b][7] = q1.w;
  }
  int vbase = blockIdx.x * 64 + wave * 16;
  for (int i = 0; i < 16; i++) {
    int v = vbase + i;
    const float* row = wte + (long)v * 512 + lane * 8;
    float4 x0 = *(const float4*)row;
    float4 x1 = *(const float4*)(row + 4);
    float xr[8] = {x0.x, x0.y, x0.z, x0.w, x1.x, x1.y, x1.z, x1.w};
    float d0 = 0, d1 = 0, d2 = 0, d3 = 0;
#pragma unroll
    for (int j = 0; j < 8; j++) {
      d0 += o[0][j] * xr[j]; d1 += o[1][j] * xr[j];
      d2 += o[2][j] * xr[j]; d3 += o[3][j] * xr[j];
    }
    for (int off = 32; off > 0; off >>= 1) {
      d0 += __shfl_down(d0, off); d1 += __shfl_down(d1, off);
      d2 += __shfl_down(d2, off); d3 += __shfl_down(d3, off);
    }
    if (lane == 0) {
      out[v] = d0; out[32000 + v] = d1; out[64000 + v] = d2;
      out[96000 + v] = d3;
    }
  }
}

// ---------------------------------------------------------------------------
extern "C" void kernel_launch(void* const* d_in, const int* in_sizes, int n_in,
                              void* d_out, int out_size, void* d_ws,
                              size_t ws_size, hipStream_t stream) {
  (void)in_sizes; (void)n_in; (void)out_size;
  const int* x = (const int*)d_in[0];
  const float* wte = (const float*)d_in[1];
  const float* wpe = (const float*)d_in[2];
  const float* g_e = (const float*)d_in[3];
  const float* g_p = (const float*)d_in[4];
  const float* g_f = (const float*)d_in[5];
  const float* W_q = (const float*)d_in[6];
  const float* W_k = (const float*)d_in[7];
  const float* W_o = (const float*)d_in[8];
  float* out = (float*)d_out;

  char* ws = (char*)d_ws;
  size_t off = 0;
  auto alloc = [&](size_t b) {
    size_t o = off;
    off += (b + 255) & ~(size_t)255;
    return o;
  };
  short* wte16 = (short*)(ws + alloc(32000L * 512 * 2));
  short* wteT16 = (short*)(ws + alloc(32000L * 512 * 2));
  short* wqt_hi = (short*)(ws + alloc(4L * 512 * 512 * 2));
  short* wqt_lo = (short*)(ws + alloc(4L * 512 * 512 * 2));
  short* wkt_hi = (short*)(ws + alloc(4L * 512 * 512 * 2));
  short* wkt_lo = (short*)(ws + alloc(4L * 512 * 512 * 2));
  short* wo16 = (short*)(ws + alloc(512L * 2048 * 2));
  short* p_hi = (short*)(ws + alloc(513L * 512 * 2));
  short* p_lo = (short*)(ws + alloc(513L * 512 * 2));
  float* e32 = (float*)(ws + alloc(2048L * 512 * 4));
  float* colmean = (float*)(ws + alloc(512 * 4));
  float* Q32 = (float*)(ws + alloc(4L * 512 * 512 * 4));
  float* K32 = (float*)(ws + alloc(4L * 512 * 512 * 4));
  short* q_hi = (short*)(ws + alloc(4L * 512 * 512 * 2));
  short* q_lo = (short*)(ws + alloc(4L * 512 * 512 * 2));
  short* k_hi = (short*)(ws + alloc(4L * 512 * 512 * 2));
  short* k_lo = (short*)(ws + alloc(4L * 512 * 512 * 2));
  float* sATT = (float*)(ws + alloc(4L * 512 * 512 * 4));
  float* krn32 = (float*)(ws + alloc(4L * 512 * 512 * 4));
  short* krn16 = (short*)(ws + alloc(4L * 512 * 512 * 2));
  short* S16 = (short*)(ws + alloc(2048L * 32000 * 2));
  float* exw32 = (float*)(ws + alloc(2048L * 512 * 4));
  float* vm32 = (float*)(ws + alloc(2048L * 512 * 4));
  short* vmT16 = (short*)(ws + alloc(2048L * 512 * 2));
  short* delta16 = (short*)(ws + alloc(2048L * 2048 * 2));
  float* fk32 = (float*)(ws + alloc(2048L * 512 * 4));
  short* fk16 = (short*)(ws + alloc(2048L * 512 * 2));
  float* flast = (float*)(ws + alloc(4L * 512 * 4));
  float* dl = (float*)(ws + alloc(4L * 2048 * 4));
  float* outln = (float*)(ws + alloc(4L * 512 * 4));
  if (off > ws_size) return;  // ws too small: bail (out stays zero)

  // --- zero accumulators ---
  hipMemsetAsync(colmean, 0, 512 * 4, stream);
  hipMemsetAsync(Q32, 0, 4L * 512 * 512 * 4, stream);
  hipMemsetAsync(K32, 0, 4L * 512 * 512 * 4, stream);
  hipMemsetAsync(sATT, 0, 4L * 512 * 512 * 4, stream);
  hipMemsetAsync(fk32, 0, 2048L * 512 * 4, stream);
  hipMemsetAsync(flast, 0, 4L * 512 * 4, stream);

  // --- setup casts / transposes ---
  cast_hilo<<<16000, 256, 0, stream>>>(wte, wte16, nullptr, 32000L * 512 / 4);
  colmean_k<<<125, 256, 0, stream>>>(wte, colmean);
  transpose_cast<<<dim3(8, 500, 1), 256, 0, stream>>>(wte, wteT16, nullptr,
                                                      32000, 512);
  transpose_cast<<<dim3(8, 8, 4), 256, 0, stream>>>(W_q, wqt_hi, wqt_lo, 512,
                                                    512);
  transpose_cast<<<dim3(8, 8, 4), 256, 0, stream>>>(W_k, wkt_hi, wkt_lo, 512,
                                                    512);
  cast_hilo<<<1024, 256, 0, stream>>>(W_o, wo16, nullptr, 512L * 2048 / 4);
  ln_rows<<<2048, 256, 0, stream>>>(nullptr, x, wte, g_e, e32, nullptr, nullptr,
                                    0);
  ln_rows<<<513, 256, 0, stream>>>(wpe, nullptr, nullptr, g_p, nullptr, p_hi,
                                   p_lo, 1);

  // --- Q = x_j @ W_q[h], K = x_i @ W_k[h], split-bf16 3-term ---
  const long HS = 262144;  // 512*512
  gemm_nt<1><<<dim3(4, 4, 4), 256, 0, stream>>>(p_hi + 512, wqt_hi, Q32, 512,
                                                512, 512, 512, 0, 4, 0, 0, 0,
                                                HS, 0, HS);
  gemm_nt<1><<<dim3(4, 4, 4), 256, 0, stream>>>(p_hi + 512, wqt_lo, Q32, 512,
                                                512, 512, 512, 0, 4, 0, 0, 0,
                                                HS, 0, HS);
  gemm_nt<1><<<dim3(4, 4, 4), 256, 0, stream>>>(p_lo + 512, wqt_hi, Q32, 512,
                                                512, 512, 512, 0, 4, 0, 0, 0,
                                                HS, 0, HS);
  gemm_nt<1><<<dim3(4, 4, 4), 256, 0, stream>>>(p_hi, wkt_hi, K32, 512, 512,
                                                512, 512, 0, 4, 0, 0, 0, HS, 0,
                                                HS);
  gemm_nt<1><<<dim3(4, 4, 4), 256, 0, stream>>>(p_hi, wkt_lo, K32, 512, 512,
                                                512, 512, 0, 4, 0, 0, 0, HS, 0,
                                                HS);
  gemm_nt<1><<<dim3(4, 4, 4), 256, 0, stream>>>(p_lo, wkt_hi, K32, 512, 512,
                                                512, 512, 0, 4, 0, 0, 0, HS, 0,
                                                HS);
  cast_hilo<<<1024, 256, 0, stream>>>(Q32, q_hi, q_lo, 262144);
  cast_hilo<<<1024, 256, 0, stream>>>(K32, k_hi, k_lo, 262144);
  // raw attention scores = Q @ K^T (3-term)
  gemm_nt<1><<<dim3(4, 4, 4), 256, 0, stream>>>(q_hi, k_hi, sATT, 512, 512, 512,
                                                512, 0, 4, 0, HS, 0, HS, 0, HS);
  gemm_nt<1><<<dim3(4, 4, 4), 256, 0, stream>>>(q_hi, k_lo, sATT, 512, 512, 512,
                                                512, 0, 4, 0, HS, 0, HS, 0, HS);
  gemm_nt<1><<<dim3(4, 4, 4), 256, 0, stream>>>(q_lo, k_hi, sATT, 512, 512, 512,
                                                512, 0, 4, 0, HS, 0, HS, 0, HS);
  softmax_krn_k<<<2048, 256, 0, stream>>>(sATT, krn32, krn16);

  // --- layer loop ---
  for (int l = 0; l < 4; ++l) {
    if (l > 0) {
      // scores = f_k @ wte^T  (M=2048, N=32000, K=512), raw bf16
      gemm_nt<0><<<dim3(16, 250, 1), 256, 0, stream>>>(
          fk16, wte16, S16, 512, 512, 32000, 512, 0, 1, 0, 0, 0, 0, 0, 0);
      softmax_vocab<<<2048, 256, 0, stream>>>(S16);
      hipMemsetAsync(exw32, 0, 2048L * 512 * 4, stream);
      // ex_wte = P @ wte  (M=2048, N=512, K=32000), split-K=8, fp32 atomics
      gemm_nt<1><<<dim3(16, 4, 8), 256, 0, stream>>>(
          S16, wteT16, exw32, 32000, 32000, 512, 4000, 4000, 8, 0, 0, 0, 0, 0,
          0);
    }
    vm_k<<<dim3(8, 8, 4), 256, 0, stream>>>(e32, exw32, colmean,
                                            (l == 0) ? 1 : 0, vm32, vmT16);
    // delta[b,h] = krn[h] @ Vm[b], scaled by coef[s], packed (b,s,h*512+e)
    gemm_nt<2><<<dim3(4, 4, 16), 256, 0, stream>>>(
        krn16, vmT16, delta16, 512, 512, 2048, 512, 0, 4, 0, HS, HS, 0,
        1048576L, 512);
    // f_k += delta @ W_o^T  (M=2048, N=512, K=2048), split-K=4
    gemm_nt<1><<<dim3(16, 4, 4), 256, 0, stream>>>(
        delta16, wo16, fk32, 2048, 2048, 512, 512, 512, 4, 0, 0, 0, 0, 0, 0);
    // fp32 shadow path for the last position
    dlast_k<<<16, 256, 0, stream>>>(krn32, vm32, dl);
    flast_k<<<dim3(2, 4, 1), 256, 0, stream>>>(dl, W_o, flast);
    cast_hilo<<<1024, 256, 0, stream>>>(fk32, fk16, nullptr, 262144);
  }

  // --- final LN + logits (pure fp32) ---
  ln_rows<<<4, 256, 0, stream>>>(flast, nullptr, nullptr, g_f, outln, nullptr,
                                 nullptr, 2);
  logits_k<<<500, 256, 0, stream>>>(outln, wte, out);
}

// Round 2
// 1682.747 us; speedup vs baseline: 1.0617x; 1.0617x over previous
//
#include <hip/hip_runtime.h>
#include <stdint.h>

// ---------------------------------------------------------------------------
// Shapes (fixed by the reference): V=32000, D=512, H=4, L=4, B=4, S=512
// Output: logits (4,1,32000) fp32.
// Strategy:
//  - bf16 MFMA for the big vocab GEMMs (error damped by softmax over 32000).
//  - split-bf16 (hi/lo, 3-term) MFMA for Q/K/krn (near-fp32 accuracy).
//  - fp32 shadow path for f_k[:,511,:] (the only row that reaches the output;
//    final LN amplifies by ~316 since var(f_k_last) << eps).
//  - layer 0: softmax(0) is uniform -> ex_wte = colmean(wte) exactly.
//  - R1: global_load_lds (16B) staging per m97 ladder; TERMS=3 fused
//    split-bf16 GEMM; Q+K in one launch; EPI=3 f32 store (no memset/atomics).
// ---------------------------------------------------------------------------

typedef __attribute__((ext_vector_type(8))) short s16x8;
typedef __attribute__((ext_vector_type(4))) short s16x4;
typedef __attribute__((ext_vector_type(4))) float f32x4;

__device__ __forceinline__ short f2bf(float f) {
  unsigned u = __float_as_uint(f);
  unsigned r = (u + 0x7FFFu + ((u >> 16) & 1u)) >> 16;  // RNE
  return (short)r;
}
__device__ __forceinline__ float bf2f(short u) {
  unsigned v = ((unsigned)(unsigned short)u) << 16;
  return __uint_as_float(v);
}

// Async global->LDS DMA, 16B per lane. LDS dest = wave-uniform base + lane*16.
__device__ __forceinline__ void load16(const short* g, short* l) {
  __builtin_amdgcn_global_load_lds(
      (__attribute__((address_space(1))) void*)(short*)g,
      (__attribute__((address_space(3))) void*)l, 16, 0, 0);
}

// ---------------------------------------------------------------------------
// Generic NT GEMM: C[m,n] (+)= sum_k A[m,k] * B[n,k], A (MxK), B (NxK) bf16.
// 128x128 tile, BK=32, 256 threads (4 waves, each 64x64 via 4x4 mfma 16x16x32).
// z-dim: zq=z/zdiv, zr=z%zdiv. Batch strides in *elements*. k0 = zr*k0_mul
// (split-K offset applied to both A and B).
// TERMS=3: accumulate Ag*Bg + Ag*B2g + A2g*Bg (split-bf16 hi/lo 3-term).
// EPI: 0 = store bf16; 1 = atomicAdd fp32; 2 = bf16 scaled by 1/(1+row);
//      3 = plain fp32 store.
// ---------------------------------------------------------------------------
template <int EPI, int TERMS>
__global__ void __launch_bounds__(256) gemm_nt(
    const short* __restrict__ Ag, const short* __restrict__ Bg,
    const short* __restrict__ A2g, const short* __restrict__ B2g,
    void* __restrict__ Cg, int lda, int ldb, int ldc, int klen, int k0_mul,
    int zdiv, long sAq, long sAr, long sBq, long sBr, long sCq, long sCr) {
  const int tid = threadIdx.x;
  const int z = blockIdx.z;
  const int zq = z / zdiv, zr = z % zdiv;
  const long aOff = zq * sAq + zr * sAr + (long)zr * k0_mul;
  const long bOff = zq * sBq + zr * sBr + (long)zr * k0_mul;
  const long cOff = zq * sCq + zr * sCr;

  __shared__ __align__(16) short As[128 * 32];
  __shared__ __align__(16) short Bs[128 * 32];

  const long m0 = (long)blockIdx.x * 128;
  const long n0 = (long)blockIdx.y * 128;

  const int wave = tid >> 6, lane = tid & 63;
  const int wm = (wave >> 1) * 64, wn = (wave & 1) * 64;
  const int mlan = lane & 15, kg = lane >> 4;

  f32x4 acc[4][4] = {};

  // staging geometry: each wave DMAs 32 A-rows and 32 B-rows (2x 1KiB chunks each)
  const int lr = lane >> 2;        // 0..15 row within chunk
  const int lk = (lane & 3) * 8;   // k-offset in elements (16B granules)
  const int r0w = wave * 32;

  short* la0 = As + r0w * 32 + lane * 8;
  short* la1 = la0 + 512;
  short* lb0 = Bs + r0w * 32 + lane * 8;
  short* lb1 = lb0 + 512;

  const int nk = klen >> 5;
#pragma unroll 1
  for (int t = 0; t < TERMS; ++t) {
    const short* Abase = ((TERMS == 3 && t == 2) ? A2g : Ag) + aOff;
    const short* Bbase = ((TERMS == 3 && t == 1) ? B2g : Bg) + bOff;
    const short* ga0 = Abase + (m0 + r0w + lr) * (long)lda + lk;
    const short* ga1 = ga0 + 16 * (long)lda;
    const short* gb0 = Bbase + (n0 + r0w + lr) * (long)ldb + lk;
    const short* gb1 = gb0 + 16 * (long)ldb;
#pragma unroll 1
    for (int kt = 0; kt < nk; ++kt) {
      const int kb = kt * 32;
      __syncthreads();
      load16(ga0 + kb, la0);
      load16(ga1 + kb, la1);
      load16(gb0 + kb, lb0);
      load16(gb1 + kb, lb1);
      __syncthreads();
      s16x8 af[4], bfr[4];
#pragma unroll
      for (int i = 0; i < 4; ++i) {
        af[i] = *(const s16x8*)(As + (wm + i * 16 + mlan) * 32 + kg * 8);
        bfr[i] = *(const s16x8*)(Bs + (wn + i * 16 + mlan) * 32 + kg * 8);
      }
#pragma unroll
      for (int mi = 0; mi < 4; ++mi)
#pragma unroll
        for (int ni = 0; ni < 4; ++ni)
          acc[mi][ni] = __builtin_amdgcn_mfma_f32_16x16x32_bf16(
              af[mi], bfr[ni], acc[mi][ni], 0, 0, 0);
    }
  }

  const int rq = (lane >> 4) * 4;
#pragma unroll
  for (int mi = 0; mi < 4; ++mi) {
#pragma unroll
    for (int ni = 0; ni < 4; ++ni) {
#pragma unroll
      for (int r = 0; r < 4; ++r) {
        long row = m0 + wm + mi * 16 + rq + r;   // M index
        long col = n0 + wn + ni * 16 + mlan;     // N index
        float v = acc[mi][ni][r];
        if (EPI == 1) {
          atomicAdd((float*)Cg + cOff + row * (long)ldc + col, v);
        } else if (EPI == 3) {
          ((float*)Cg)[cOff + row * (long)ldc + col] = v;
        } else {
          if (EPI == 2) v *= 1.0f / (1.0f + (float)row);
          *((short*)Cg + cOff + row * (long)ldc + col) = f2bf(v);
        }
      }
    }
  }
}

// ---------------------------------------------------------------------------
// LayerNorm of 512-wide rows. mode 0: gather wte[x[r]] -> o32 (e).
// mode 1: src rows -> hi/lo bf16 (p). mode 2: src rows -> o32 (final LN).
// ---------------------------------------------------------------------------
__global__ void __launch_bounds__(256) ln_rows(
    const float* __restrict__ src, const int* __restrict__ tok,
    const float* __restrict__ wte, const float* __restrict__ g,
    float* __restrict__ o32, short* __restrict__ ohi, short* __restrict__ olo,
    int mode) {
  int r = blockIdx.x, tid = threadIdx.x;
  const float* in;
  if (mode == 0)
    in = wte + (long)tok[r] * 512;
  else
    in = src + (long)r * 512;
  int d = tid * 2;
  float2 v = *(const float2*)(in + d);
  float s1 = v.x + v.y;
  float s2 = v.x * v.x + v.y * v.y;
  __shared__ float red[20];
  for (int o = 32; o > 0; o >>= 1) {
    s1 += __shfl_down(s1, o);
    s2 += __shfl_down(s2, o);
  }
  int wave = tid >> 6, lane = tid & 63;
  if (lane == 0) { red[wave] = s1; red[wave + 8] = s2; }
  __syncthreads();
  if (tid == 0) {
    float a = red[0] + red[1] + red[2] + red[3];
    float b = red[8] + red[9] + red[10] + red[11];
    float mean = a * (1.f / 512.f);
    float var = b * (1.f / 512.f) - mean * mean;
    red[16] = mean;
    red[17] = 1.0f / sqrtf(var + 1e-5f);
  }
  __syncthreads();
  float mean = red[16], rs = red[17];
  float2 gg = *(const float2*)(g + d);
  float y0 = (v.x - mean) * rs * gg.x;
  float y1 = (v.y - mean) * rs * gg.y;
  long o = (long)r * 512 + d;
  if (o32) { o32[o] = y0; o32[o + 1] = y1; }
  if (ohi) {
    short h0 = f2bf(y0), h1 = f2bf(y1);
    ohi[o] = h0; ohi[o + 1] = h1;
    if (olo) {
      olo[o] = f2bf(y0 - bf2f(h0));
      olo[o + 1] = f2bf(y1 - bf2f(h1));
    }
  }
}

// In-place softmax over each row of S (2048 rows x 32000 bf16).
__global__ void __launch_bounds__(256) softmax_vocab(short* __restrict__ S) {
  const int NV = 32000 / 8;
  long base = (long)blockIdx.x * 32000;
  int tid = threadIdx.x;
  float m = -3.0e38f, l = 0.f;
  for (int i = tid; i < NV; i += 256) {
    s16x8 v = *(const s16x8*)(S + base + (long)i * 8);
    float x[8];
#pragma unroll
    for (int j = 0; j < 8; j++) x[j] = bf2f(v[j]);
    float mv = x[0];
#pragma unroll
    for (int j = 1; j < 8; j++) mv = fmaxf(mv, x[j]);
    if (mv > m) { l *= __expf(m - mv); m = mv; }
#pragma unroll
    for (int j = 0; j < 8; j++) l += __expf(x[j] - m);
  }
  for (int o = 32; o > 0; o >>= 1) {
    float m2 = __shfl_down(m, o), l2 = __shfl_down(l, o);
    float mn = fmaxf(m, m2);
    l = l * __expf(m - mn) + l2 * __expf(m2 - mn);
    m = mn;
  }
  __shared__ float sm[8], sl[8];
  int wave = tid >> 6, lane = tid & 63;
  if (lane == 0) { sm[wave] = m; sl[wave] = l; }
  __syncthreads();
  if (tid == 0) {
    float M = sm[0], L = sl[0];
    for (int w = 1; w < 4; w++) {
      float mn = fmaxf(M, sm[w]);
      L = L * __expf(M - mn) + sl[w] * __expf(sm[w] - mn);
      M = mn;
    }
    sm[4] = M; sl[4] = 1.0f / L;
  }
  __syncthreads();
  float M = sm[4], IL = sl[4];
  for (int i = tid; i < NV; i += 256) {
    s16x8 v = *(const s16x8*)(S + base + (long)i * 8);
    s16x8 o;
#pragma unroll
    for (int j = 0; j < 8; j++) o[j] = f2bf(__expf(bf2f(v[j]) - M) * IL);
    *(s16x8*)(S + base + (long)i * 8) = o;
  }
}

// Attention softmax: raw (H,S,S) fp32 -> scale, clip(+-10), causal, softmax.
__global__ void __launch_bounds__(256) softmax_krn_k(
    const float* __restrict__ raw, float* __restrict__ k32,
    short* __restrict__ k16) {
  int bx = blockIdx.x;
  int h = bx >> 9, s = bx & 511;
  long base = ((long)h * 512 + s) * 512;
  int tid = threadIdx.x;
  const float scale = 0.04419417382415922f;  // 1/sqrt(512)
  float e0 = 0.f, e1 = 0.f, l = 0.f;
  int t0 = tid, t1 = tid + 256;
  if (t0 <= s) {
    float v = raw[base + t0] * scale;
    v = fminf(fmaxf(v, -10.f), 10.f);
    e0 = __expf(v); l += e0;
  }
  if (t1 <= s) {
    float v = raw[base + t1] * scale;
    v = fminf(fmaxf(v, -10.f), 10.f);
    e1 = __expf(v); l += e1;
  }
  for (int o = 32; o > 0; o >>= 1) l += __shfl_down(l, o);
  __shared__ float red[10];
  int wave = tid >> 6, lane = tid & 63;
  if (lane == 0) red[wave] = l;
  __syncthreads();
  if (tid == 0) red[8] = 1.0f / (red[0] + red[1] + red[2] + red[3]);
  __syncthreads();
  float inv = red[8];
  k32[base + t0] = e0 * inv;
  k16[base + t0] = f2bf(e0 * inv);
  k32[base + t1] = e1 * inv;
  k16[base + t1] = f2bf(e1 * inv);
}

// Transpose+cast: in (RxC) f32 -> out (CxR) bf16 hi (and optional lo).
__global__ void __launch_bounds__(256) transpose_cast(
    const float* __restrict__ in, short* __restrict__ hi,
    short* __restrict__ lo, int R, int C) {
  long bo = (long)blockIdx.z * R * C;
  const float* inp = in + bo;
  short* ho = hi + bo;
  short* lop = lo ? lo + bo : nullptr;
  int c0 = blockIdx.x * 64, r0 = blockIdx.y * 64;
  __shared__ float tl[64][65];
  int tid = threadIdx.x;
  for (int it = 0; it < 16; ++it) {
    int idx = it * 256 + tid;
    int rr = idx >> 6, cc = idx & 63;
    tl[rr][cc] = inp[(long)(r0 + rr) * C + (c0 + cc)];
  }
  __syncthreads();
  for (int it = 0; it < 16; ++it) {
    int idx = it * 256 + tid;
    int rr = idx >> 6, cc = idx & 63;
    float v = tl[cc][rr];
    long o = (long)(c0 + rr) * R + (r0 + cc);
    short hh = f2bf(v);
    ho[o] = hh;
    if (lop) lop[o] = f2bf(v - bf2f(hh));
  }
}

// Elementwise f32 -> bf16 hi (and optional lo residual). n4 = n/4.
__global__ void __launch_bounds__(256) cast_hilo(
    const float* __restrict__ in, short* __restrict__ hi,
    short* __restrict__ lo, long n4) {
  long i = (long)blockIdx.x * 256 + threadIdx.x;
  if (i >= n4) return;
  float4 v = ((const float4*)in)[i];
  s16x4 h;
  h[0] = f2bf(v.x); h[1] = f2bf(v.y); h[2] = f2bf(v.z); h[3] = f2bf(v.w);
  *(s16x4*)(hi + i * 4) = h;
  if (lo) {
    s16x4 L;
    L[0] = f2bf(v.x - bf2f(h[0])); L[1] = f2bf(v.y - bf2f(h[1]));
    L[2] = f2bf(v.z - bf2f(h[2])); L[3] = f2bf(v.w - bf2f(h[3]));
    *(s16x4*)(lo + i * 4) = L;
  }
}

// Column mean of wte (32000x512) -> cm[512]. Grid 125, 256 rows per block.
__global__ void __launch_bounds__(256) colmean_k(const float* __restrict__ wte,
                                                 float* __restrict__ cm) {
  int d = threadIdx.x * 2;
  long r0 = (long)blockIdx.x * 256;
  float a0 = 0.f, a1 = 0.f;
  for (int r = 0; r < 256; r++) {
    float2 v = *(const float2*)(wte + (r0 + r) * 512 + d);
    a0 += v.x; a1 += v.y;
  }
  atomicAdd(&cm[d], a0 * (1.f / 32000.f));
  atomicAdd(&cm[d + 1], a1 * (1.f / 32000.f));
}

// Vm = e - ex_wte (or colmean at layer 0): writes vm32 and vmT16 (b,e,t).
__global__ void __launch_bounds__(256) vm_k(
    const float* __restrict__ e32, const float* __restrict__ exw,
    const float* __restrict__ cm, int useCm, float* __restrict__ vm32,
    short* __restrict__ vmT) {
  int b = blockIdx.z, t0 = blockIdx.y * 64, e0 = blockIdx.x * 64;
  __shared__ short tl[64][72];
  int tid = threadIdx.x;
  long base = ((long)b * 512 + t0) * 512 + e0;
  for (int it = 0; it < 16; ++it) {
    int idx = it * 256 + tid;
    int rr = idx >> 6, cc = idx & 63;
    long o = base + (long)rr * 512 + cc;
    float v = e32[o] - (useCm ? cm[e0 + cc] : exw[o]);
    vm32[o] = v;
    tl[rr][cc] = f2bf(v);
  }
  __syncthreads();
  for (int it = 0; it < 16; ++it) {
    int idx = it * 256 + tid;
    int rr = idx >> 6, cc = idx & 63;
    vmT[((long)b * 512 + (e0 + rr)) * 512 + (t0 + cc)] = tl[cc][rr];
  }
}

// Shadow fp32 path, step 1: delta_last[b, h*512+e] = coef[511]*sum_t krn[h,511,t]*Vm[b,t,e]
__global__ void __launch_bounds__(256) dlast_k(
    const float* __restrict__ krn32, const float* __restrict__ vm32,
    float* __restrict__ dl) {
  int b = blockIdx.x >> 2, h = blockIdx.x & 3;
  int tid = threadIdx.x;
  __shared__ float w[512];
  long kb = ((long)h * 512 + 511) * 512;
  w[tid] = krn32[kb + tid];
  w[tid + 256] = krn32[kb + tid + 256];
  __syncthreads();
  float a0 = 0.f, a1 = 0.f;
  int e0 = tid, e1 = tid + 256;
  const float* vb = vm32 + (long)b * 512 * 512;
  for (int t = 0; t < 512; t++) {
    float wt = w[t];
    a0 += wt * vb[(long)t * 512 + e0];
    a1 += wt * vb[(long)t * 512 + e1];
  }
  dl[(long)b * 2048 + h * 512 + e0] = a0 * (1.f / 512.f);
  dl[(long)b * 2048 + h * 512 + e1] = a1 * (1.f / 512.f);
}

// Shadow step 2: f_last[b,d] += sum_k dl[b,k] * W_o[d,k]   (fp32)
__global__ void __launch_bounds__(256) flast_k(
    const float* __restrict__ dl, const float* __restrict__ Wo,
    float* __restrict__ fl) {
  int b = blockIdx.y, d = blockIdx.x * 256 + threadIdx.x;
  __shared__ float ds_[2048];
  for (int i = threadIdx.x; i < 2048; i += 256) ds_[i] = dl[(long)b * 2048 + i];
  __syncthreads();
  const float* wr = Wo + (long)d * 2048;
  float acc = 0.f;
  for (int k = 0; k < 2048; k += 4) {
    float4 wv = *(const float4*)(wr + k);
    acc += ds_[k] * wv.x + ds_[k + 1] * wv.y + ds_[k + 2] * wv.z +
           ds_[k + 3] * wv.w;
  }
  fl[(long)b * 512 + d] += acc;
}

// logits[b,v] = dot(outln[b,:], wte[v,:]) fp32. One wave handles 16 rows.
__global__ void __launch_bounds__(256) logits_k(
    const float* __restrict__ outln, const float* __restrict__ wte,
    float* __restrict__ out) {
  int tid = threadIdx.x, wave = tid >> 6, lane = tid & 63;
  float o[4][8];
#pragma unroll
  for (int b = 0; b < 4; b++) {
    float4 q0 = *(const float4*)(outln + b * 512 + lane * 8);
    float4 q1 = *(const float4*)(outln + b * 512 + lane * 8 + 4);
    o[b][0] = q0.x; o[b][1] = q0.y; o[b][2] = q0.z; o[b][3] = q0.w;
    o[b][4] = q1.x; o[b][5] = q1.y; o[b][6] = q1.z; o[b][7] = q1.w;
  }
  int vbase = blockIdx.x * 64 + wave * 16;
  for (int i = 0; i < 16; i++) {
    int v = vbase + i;
    const float* row = wte + (long)v * 512 + lane * 8;
    float4 x0 = *(const float4*)row;
    float4 x1 = *(const float4*)(row + 4);
    float xr[8] = {x0.x, x0.y, x0.z, x0.w, x1.x, x1.y, x1.z, x1.w};
    float d0 = 0, d1 = 0, d2 = 0, d3 = 0;
#pragma unroll
    for (int j = 0; j < 8; j++) {
      d0 += o[0][j] * xr[j]; d1 += o[1][j] * xr[j];
      d2 += o[2][j] * xr[j]; d3 += o[3][j] * xr[j];
    }
    for (int off = 32; off > 0; off >>= 1) {
      d0 += __shfl_down(d0, off); d1 += __shfl_down(d1, off);
      d2 += __shfl_down(d2, off); d3 += __shfl_down(d3, off);
    }
    if (lane == 0) {
      out[v] = d0; out[32000 + v] = d1; out[64000 + v] = d2;
      out[96000 + v] = d3;
    }
  }
}

// ---------------------------------------------------------------------------
extern "C" void kernel_launch(void* const* d_in, const int* in_sizes, int n_in,
                              void* d_out, int out_size, void* d_ws,
                              size_t ws_size, hipStream_t stream) {
  (void)in_sizes; (void)n_in; (void)out_size;
  const int* x = (const int*)d_in[0];
  const float* wte = (const float*)d_in[1];
  const float* wpe = (const float*)d_in[2];
  const float* g_e = (const float*)d_in[3];
  const float* g_p = (const float*)d_in[4];
  const float* g_f = (const float*)d_in[5];
  const float* W_q = (const float*)d_in[6];
  const float* W_k = (const float*)d_in[7];
  const float* W_o = (const float*)d_in[8];
  float* out = (float*)d_out;

  char* ws = (char*)d_ws;
  size_t off = 0;
  auto alloc = [&](size_t b) {
    size_t o = off;
    off += (b + 255) & ~(size_t)255;
    return o;
  };
  const long HS = 262144;  // 512*512
  short* wte16 = (short*)(ws + alloc(32000L * 512 * 2));
  short* wteT16 = (short*)(ws + alloc(32000L * 512 * 2));
  // W_q^T and W_k^T contiguous (hi then hi, lo then lo) for the fused launch
  short* wqkt_hi = (short*)(ws + alloc(8L * HS * 2));
  short* wqkt_lo = (short*)(ws + alloc(8L * HS * 2));
  short* wo16 = (short*)(ws + alloc(512L * 2048 * 2));
  short* p_hi = (short*)(ws + alloc(513L * 512 * 2));
  short* p_lo = (short*)(ws + alloc(513L * 512 * 2));
  float* e32 = (float*)(ws + alloc(2048L * 512 * 4));
  float* colmean = (float*)(ws + alloc(512 * 4));
  float* QK32 = (float*)(ws + alloc(8L * HS * 4));  // Q (4 heads) then K
  short* qk_hi = (short*)(ws + alloc(8L * HS * 2));
  short* qk_lo = (short*)(ws + alloc(8L * HS * 2));
  float* sATT = (float*)(ws + alloc(4L * HS * 4));
  float* krn32 = (float*)(ws + alloc(4L * HS * 4));
  short* krn16 = (short*)(ws + alloc(4L * HS * 2));
  short* S16 = (short*)(ws + alloc(2048L * 32000 * 2));
  float* exw32 = (float*)(ws + alloc(2048L * 512 * 4));
  float* vm32 = (float*)(ws + alloc(2048L * 512 * 4));
  short* vmT16 = (short*)(ws + alloc(2048L * 512 * 2));
  short* delta16 = (short*)(ws + alloc(2048L * 2048 * 2));
  float* fk32 = (float*)(ws + alloc(2048L * 512 * 4));
  short* fk16 = (short*)(ws + alloc(2048L * 512 * 2));
  float* flast = (float*)(ws + alloc(4L * 512 * 4));
  float* dl = (float*)(ws + alloc(4L * 2048 * 4));
  float* outln = (float*)(ws + alloc(4L * 512 * 4));
  if (off > ws_size) return;  // ws too small: bail (out stays zero)

  // --- zero accumulators ---
  hipMemsetAsync(colmean, 0, 512 * 4, stream);
  hipMemsetAsync(fk32, 0, 2048L * 512 * 4, stream);
  hipMemsetAsync(flast, 0, 4L * 512 * 4, stream);

  // --- setup casts / transposes ---
  cast_hilo<<<16000, 256, 0, stream>>>(wte, wte16, nullptr, 32000L * 512 / 4);
  colmean_k<<<125, 256, 0, stream>>>(wte, colmean);
  transpose_cast<<<dim3(8, 500, 1), 256, 0, stream>>>(wte, wteT16, nullptr,
                                                      32000, 512);
  transpose_cast<<<dim3(8, 8, 4), 256, 0, stream>>>(W_q, wqkt_hi, wqkt_lo, 512,
                                                    512);
  transpose_cast<<<dim3(8, 8, 4), 256, 0, stream>>>(
      W_k, wqkt_hi + 4 * HS, wqkt_lo + 4 * HS, 512, 512);
  cast_hilo<<<1024, 256, 0, stream>>>(W_o, wo16, nullptr, 512L * 2048 / 4);
  ln_rows<<<2048, 256, 0, stream>>>(nullptr, x, wte, g_e, e32, nullptr, nullptr,
                                    0);
  ln_rows<<<513, 256, 0, stream>>>(wpe, nullptr, nullptr, g_p, nullptr, p_hi,
                                   p_lo, 1);

  // --- Q|K = x_j|x_i @ W_q|W_k, one fused 3-term launch ---
  // z = zq*4 + head; zq=0 -> Q (A = p+512), zq=1 -> K (A = p).
  gemm_nt<3, 3><<<dim3(4, 4, 8), 256, 0, stream>>>(
      p_hi + 512, wqkt_hi, p_lo + 512, wqkt_lo, QK32, 512, 512, 512, 512, 0, 4,
      /*sAq*/ -512, /*sAr*/ 0, /*sBq*/ 4 * HS, /*sBr*/ HS, /*sCq*/ 4 * HS,
      /*sCr*/ HS);
  cast_hilo<<<2048, 256, 0, stream>>>(QK32, qk_hi, qk_lo, 8 * HS / 4);
  // raw attention scores = Q @ K^T, one fused 3-term launch
  gemm_nt<3, 3><<<dim3(4, 4, 4), 256, 0, stream>>>(
      qk_hi, qk_hi + 4 * HS, qk_lo, qk_lo + 4 * HS, sATT, 512, 512, 512, 512,
      0, 4, 0, HS, 0, HS, 0, HS);
  softmax_krn_k<<<2048, 256, 0, stream>>>(sATT, krn32, krn16);

  // --- layer loop ---
  for (int l = 0; l < 4; ++l) {
    if (l > 0) {
      // scores = f_k @ wte^T  (M=2048, N=32000, K=512), raw bf16
      gemm_nt<0, 1><<<dim3(16, 250, 1), 256, 0, stream>>>(
          fk16, wte16, nullptr, nullptr, S16, 512, 512, 32000, 512, 0, 1, 0, 0,
          0, 0, 0, 0);
      softmax_vocab<<<2048, 256, 0, stream>>>(S16);
      hipMemsetAsync(exw32, 0, 2048L * 512 * 4, stream);
      // ex_wte = P @ wte  (M=2048, N=512, K=32000), split-K=8, fp32 atomics
      gemm_nt<1, 1><<<dim3(16, 4, 8), 256, 0, stream>>>(
          S16, wteT16, nullptr, nullptr, exw32, 32000, 32000, 512, 4000, 4000,
          8, 0, 0, 0, 0, 0, 0);
    }
    vm_k<<<dim3(8, 8, 4), 256, 0, stream>>>(e32, exw32, colmean,
                                            (l == 0) ? 1 : 0, vm32, vmT16);
    // delta[b,h] = krn[h] @ Vm[b], scaled by coef[s], packed (b,s,h*512+e)
    gemm_nt<2, 1><<<dim3(4, 4, 16), 256, 0, stream>>>(
        krn16, vmT16, nullptr, nullptr, delta16, 512, 512, 2048, 512, 0, 4, 0,
        HS, HS, 0, 1048576L, 512);
    // f_k += delta @ W_o^T  (M=2048, N=512, K=2048), split-K=4
    gemm_nt<1, 1><<<dim3(16, 4, 4), 256, 0, stream>>>(
        delta16, wo16, nullptr, nullptr, fk32, 2048, 2048, 512, 512, 512, 4, 0,
        0, 0, 0, 0, 0);
    // fp32 shadow path for the last position
    dlast_k<<<16, 256, 0, stream>>>(krn32, vm32, dl);
    flast_k<<<dim3(2, 4, 1), 256, 0, stream>>>(dl, W_o, flast);
    cast_hilo<<<1024, 256, 0, stream>>>(fk32, fk16, nullptr, 262144);
  }

  // --- final LN + logits (pure fp32) ---
  ln_rows<<<4, 256, 0, stream>>>(flast, nullptr, nullptr, g_f, outln, nullptr,
                                 nullptr, 2);
  logits_k<<<500, 256, 0, stream>>>(outln, wte, out);
}

// Round 3
// 1518.551 us; speedup vs baseline: 1.1765x; 1.1081x over previous
//
#include <hip/hip_runtime.h>
#include <stdint.h>

// ---------------------------------------------------------------------------
// Shapes (fixed by the reference): V=32000, D=512, H=4, L=4, B=4, S=512
// Output: logits (4,1,32000) fp32.
// Strategy:
//  - bf16 MFMA for the big vocab GEMMs (error damped by softmax over 32000).
//  - split-bf16 (hi/lo, 3-term) MFMA for Q/K/krn (near-fp32 accuracy).
//  - fp32 shadow path for f_k[:,511,:] (the only row that reaches the output;
//    final LN amplifies by ~316 since var(f_k_last) << eps).
//  - layer 0: softmax(0) is uniform -> ex_wte = colmean(wte) exactly.
//  - R2: BK=64 (half the barriers), XOR-swizzled LDS (kills 8-way ds_read
//    bank conflicts; staging stays DMA-contiguous), ex_wte split-K 10,
//    EPI=4 direct hi/lo store (drops QK32 round trip).
// ---------------------------------------------------------------------------

typedef __attribute__((ext_vector_type(8))) short s16x8;
typedef __attribute__((ext_vector_type(4))) short s16x4;
typedef __attribute__((ext_vector_type(4))) float f32x4;

__device__ __forceinline__ short f2bf(float f) {
  unsigned u = __float_as_uint(f);
  unsigned r = (u + 0x7FFFu + ((u >> 16) & 1u)) >> 16;  // RNE
  return (short)r;
}
__device__ __forceinline__ float bf2f(short u) {
  unsigned v = ((unsigned)(unsigned short)u) << 16;
  return __uint_as_float(v);
}

// Async global->LDS DMA, 16B per lane. LDS dest = wave-uniform base + lane*16.
__device__ __forceinline__ void load16(const short* g, short* l) {
  __builtin_amdgcn_global_load_lds(
      (__attribute__((address_space(1))) void*)(short*)g,
      (__attribute__((address_space(3))) void*)l, 16, 0, 0);
}

// ---------------------------------------------------------------------------
// Generic NT GEMM: C[m,n] (+)= sum_k A[m,k] * B[n,k], A (MxK), B (NxK) bf16.
// 128x128 tile, BK=64, 256 threads (4 waves, each 64x64 via 4x4 mfma 16x16x32).
// LDS layout swizzled: (row r, 16B-granule g) lives at r*128B + ((g^(r&7))*16B)
// -> staging is contiguous per lane (DMA-safe), fragment ds_read_b128 is
// 2-way-aliased only (free per m136).
// z-dim: zq=z/zdiv, zr=z%zdiv. Batch strides in *elements*. k0 = zr*k0_mul.
// TERMS=3: accumulate Ag*Bg + Ag*B2g + A2g*Bg (split-bf16 hi/lo 3-term).
// EPI: 0 = store bf16; 1 = atomicAdd fp32; 2 = bf16 scaled by 1/(1+row);
//      3 = plain fp32 store; 4 = store bf16 hi to Cg and lo residual to C2g.
// ---------------------------------------------------------------------------
template <int EPI, int TERMS>
__global__ void __launch_bounds__(256) gemm_nt(
    const short* __restrict__ Ag, const short* __restrict__ Bg,
    const short* __restrict__ A2g, const short* __restrict__ B2g,
    void* __restrict__ Cg, short* __restrict__ C2g, int lda, int ldb, int ldc,
    int klen, int k0_mul, int zdiv, long sAq, long sAr, long sBq, long sBr,
    long sCq, long sCr) {
  const int tid = threadIdx.x;
  const int z = blockIdx.z;
  const int zq = z / zdiv, zr = z % zdiv;
  const long aOff = zq * sAq + zr * sAr + (long)zr * k0_mul;
  const long bOff = zq * sBq + zr * sBr + (long)zr * k0_mul;
  const long cOff = zq * sCq + zr * sCr;

  __shared__ __align__(16) short As[128 * 64];
  __shared__ __align__(16) short Bs[128 * 64];

  const long m0 = (long)blockIdx.x * 128;
  const long n0 = (long)blockIdx.y * 128;

  const int wave = tid >> 6, lane = tid & 63;
  const int wm = (wave >> 1) * 64, wn = (wave & 1) * 64;
  const int mlan = lane & 15, kg = lane >> 4;

  f32x4 acc[4][4] = {};

  // staging: per wave 32 rows of A and 32 rows of B, 4 DMA instrs each.
  // instr j covers rows [wave*32 + j*8, +8); lane -> row wave*32+j*8+(lane>>3),
  // LDS granule m = lane&7, which holds source k-granule g = m ^ (row&7).
  const int g_src = ((lane & 7) ^ (lane >> 3)) * 8;  // element offset
  const int lrow = lane >> 3;                        // 0..7
  short* lA = As + wave * 2048 + lane * 8;
  short* lB = Bs + wave * 2048 + lane * 8;

  // fragment read swizzle: row = wm|wn + i*16 + mlan, k-granule kg (+4 for
  // the second k-half) -> element offset ((kg ^ (row&7))*8), row&7 == mlan&7.
  const int gi0 = ((kg ^ (mlan & 7)) * 8);
  const int gi1 = gi0 ^ 32;

  const int nk = klen >> 6;
#pragma unroll 1
  for (int t = 0; t < TERMS; ++t) {
    const short* Abase = ((TERMS == 3 && t == 2) ? A2g : Ag) + aOff;
    const short* Bbase = ((TERMS == 3 && t == 1) ? B2g : Bg) + bOff;
    const short* ga = Abase + (m0 + wave * 32 + lrow) * (long)lda + g_src;
    const short* gb = Bbase + (n0 + wave * 32 + lrow) * (long)ldb + g_src;
#pragma unroll 1
    for (int kt = 0; kt < nk; ++kt) {
      const int kb = kt * 64;
      __syncthreads();
      load16(ga + kb, lA);
      load16(ga + 8 * (long)lda + kb, lA + 512);
      load16(ga + 16 * (long)lda + kb, lA + 1024);
      load16(ga + 24 * (long)lda + kb, lA + 1536);
      load16(gb + kb, lB);
      load16(gb + 8 * (long)ldb + kb, lB + 512);
      load16(gb + 16 * (long)ldb + kb, lB + 1024);
      load16(gb + 24 * (long)ldb + kb, lB + 1536);
      __syncthreads();
      s16x8 af[2][4], bq[2][4];
      const short* pA = As + (wm + mlan) * 64;
      const short* pB = Bs + (wn + mlan) * 64;
#pragma unroll
      for (int i = 0; i < 4; ++i) {
        af[0][i] = *(const s16x8*)(pA + i * 1024 + gi0);
        af[1][i] = *(const s16x8*)(pA + i * 1024 + gi1);
        bq[0][i] = *(const s16x8*)(pB + i * 1024 + gi0);
        bq[1][i] = *(const s16x8*)(pB + i * 1024 + gi1);
      }
#pragma unroll
      for (int h = 0; h < 2; ++h)
#pragma unroll
        for (int mi = 0; mi < 4; ++mi)
#pragma unroll
          for (int ni = 0; ni < 4; ++ni)
            acc[mi][ni] = __builtin_amdgcn_mfma_f32_16x16x32_bf16(
                af[h][mi], bq[h][ni], acc[mi][ni], 0, 0, 0);
    }
  }

  const int rq = (lane >> 4) * 4;
#pragma unroll
  for (int mi = 0; mi < 4; ++mi) {
#pragma unroll
    for (int ni = 0; ni < 4; ++ni) {
#pragma unroll
      for (int r = 0; r < 4; ++r) {
        long row = m0 + wm + mi * 16 + rq + r;   // M index
        long col = n0 + wn + ni * 16 + mlan;     // N index
        float v = acc[mi][ni][r];
        long o = cOff + row * (long)ldc + col;
        if (EPI == 1) {
          atomicAdd((float*)Cg + o, v);
        } else if (EPI == 3) {
          ((float*)Cg)[o] = v;
        } else if (EPI == 4) {
          short h = f2bf(v);
          ((short*)Cg)[o] = h;
          C2g[o] = f2bf(v - bf2f(h));
        } else {
          if (EPI == 2) v *= 1.0f / (1.0f + (float)row);
          ((short*)Cg)[o] = f2bf(v);
        }
      }
    }
  }
}

// ---------------------------------------------------------------------------
// LayerNorm of 512-wide rows. mode 0: gather wte[x[r]] -> o32 (e).
// mode 1: src rows -> hi/lo bf16 (p). mode 2: src rows -> o32 (final LN).
// ---------------------------------------------------------------------------
__global__ void __launch_bounds__(256) ln_rows(
    const float* __restrict__ src, const int* __restrict__ tok,
    const float* __restrict__ wte, const float* __restrict__ g,
    float* __restrict__ o32, short* __restrict__ ohi, short* __restrict__ olo,
    int mode) {
  int r = blockIdx.x, tid = threadIdx.x;
  const float* in;
  if (mode == 0)
    in = wte + (long)tok[r] * 512;
  else
    in = src + (long)r * 512;
  int d = tid * 2;
  float2 v = *(const float2*)(in + d);
  float s1 = v.x + v.y;
  float s2 = v.x * v.x + v.y * v.y;
  __shared__ float red[20];
  for (int o = 32; o > 0; o >>= 1) {
    s1 += __shfl_down(s1, o);
    s2 += __shfl_down(s2, o);
  }
  int wave = tid >> 6, lane = tid & 63;
  if (lane == 0) { red[wave] = s1; red[wave + 8] = s2; }
  __syncthreads();
  if (tid == 0) {
    float a = red[0] + red[1] + red[2] + red[3];
    float b = red[8] + red[9] + red[10] + red[11];
    float mean = a * (1.f / 512.f);
    float var = b * (1.f / 512.f) - mean * mean;
    red[16] = mean;
    red[17] = 1.0f / sqrtf(var + 1e-5f);
  }
  __syncthreads();
  float mean = red[16], rs = red[17];
  float2 gg = *(const float2*)(g + d);
  float y0 = (v.x - mean) * rs * gg.x;
  float y1 = (v.y - mean) * rs * gg.y;
  long o = (long)r * 512 + d;
  if (o32) { o32[o] = y0; o32[o + 1] = y1; }
  if (ohi) {
    short h0 = f2bf(y0), h1 = f2bf(y1);
    ohi[o] = h0; ohi[o + 1] = h1;
    if (olo) {
      olo[o] = f2bf(y0 - bf2f(h0));
      olo[o + 1] = f2bf(y1 - bf2f(h1));
    }
  }
}

// In-place softmax over each row of S (2048 rows x 32000 bf16).
__global__ void __launch_bounds__(256) softmax_vocab(short* __restrict__ S) {
  const int NV = 32000 / 8;
  long base = (long)blockIdx.x * 32000;
  int tid = threadIdx.x;
  float m = -3.0e38f, l = 0.f;
  for (int i = tid; i < NV; i += 256) {
    s16x8 v = *(const s16x8*)(S + base + (long)i * 8);
    float x[8];
#pragma unroll
    for (int j = 0; j < 8; j++) x[j] = bf2f(v[j]);
    float mv = x[0];
#pragma unroll
    for (int j = 1; j < 8; j++) mv = fmaxf(mv, x[j]);
    if (mv > m) { l *= __expf(m - mv); m = mv; }
#pragma unroll
    for (int j = 0; j < 8; j++) l += __expf(x[j] - m);
  }
  for (int o = 32; o > 0; o >>= 1) {
    float m2 = __shfl_down(m, o), l2 = __shfl_down(l, o);
    float mn = fmaxf(m, m2);
    l = l * __expf(m - mn) + l2 * __expf(m2 - mn);
    m = mn;
  }
  __shared__ float sm[8], sl[8];
  int wave = tid >> 6, lane = tid & 63;
  if (lane == 0) { sm[wave] = m; sl[wave] = l; }
  __syncthreads();
  if (tid == 0) {
    float M = sm[0], L = sl[0];
    for (int w = 1; w < 4; w++) {
      float mn = fmaxf(M, sm[w]);
      L = L * __expf(M - mn) + sl[w] * __expf(sm[w] - mn);
      M = mn;
    }
    sm[4] = M; sl[4] = 1.0f / L;
  }
  __syncthreads();
  float M = sm[4], IL = sl[4];
  for (int i = tid; i < NV; i += 256) {
    s16x8 v = *(const s16x8*)(S + base + (long)i * 8);
    s16x8 o;
#pragma unroll
    for (int j = 0; j < 8; j++) o[j] = f2bf(__expf(bf2f(v[j]) - M) * IL);
    *(s16x8*)(S + base + (long)i * 8) = o;
  }
}

// Attention softmax: raw (H,S,S) fp32 -> scale, clip(+-10), causal, softmax.
__global__ void __launch_bounds__(256) softmax_krn_k(
    const float* __restrict__ raw, float* __restrict__ k32,
    short* __restrict__ k16) {
  int bx = blockIdx.x;
  int h = bx >> 9, s = bx & 511;
  long base = ((long)h * 512 + s) * 512;
  int tid = threadIdx.x;
  const float scale = 0.04419417382415922f;  // 1/sqrt(512)
  float e0 = 0.f, e1 = 0.f, l = 0.f;
  int t0 = tid, t1 = tid + 256;
  if (t0 <= s) {
    float v = raw[base + t0] * scale;
    v = fminf(fmaxf(v, -10.f), 10.f);
    e0 = __expf(v); l += e0;
  }
  if (t1 <= s) {
    float v = raw[base + t1] * scale;
    v = fminf(fmaxf(v, -10.f), 10.f);
    e1 = __expf(v); l += e1;
  }
  for (int o = 32; o > 0; o >>= 1) l += __shfl_down(l, o);
  __shared__ float red[10];
  int wave = tid >> 6, lane = tid & 63;
  if (lane == 0) red[wave] = l;
  __syncthreads();
  if (tid == 0) red[8] = 1.0f / (red[0] + red[1] + red[2] + red[3]);
  __syncthreads();
  float inv = red[8];
  k32[base + t0] = e0 * inv;
  k16[base + t0] = f2bf(e0 * inv);
  k32[base + t1] = e1 * inv;
  k16[base + t1] = f2bf(e1 * inv);
}

// Transpose+cast: in (RxC) f32 -> out (CxR) bf16 hi (and optional lo).
__global__ void __launch_bounds__(256) transpose_cast(
    const float* __restrict__ in, short* __restrict__ hi,
    short* __restrict__ lo, int R, int C) {
  long bo = (long)blockIdx.z * R * C;
  const float* inp = in + bo;
  short* ho = hi + bo;
  short* lop = lo ? lo + bo : nullptr;
  int c0 = blockIdx.x * 64, r0 = blockIdx.y * 64;
  __shared__ float tl[64][65];
  int tid = threadIdx.x;
  for (int it = 0; it < 16; ++it) {
    int idx = it * 256 + tid;
    int rr = idx >> 6, cc = idx & 63;
    tl[rr][cc] = inp[(long)(r0 + rr) * C + (c0 + cc)];
  }
  __syncthreads();
  for (int it = 0; it < 16; ++it) {
    int idx = it * 256 + tid;
    int rr = idx >> 6, cc = idx & 63;
    float v = tl[cc][rr];
    long o = (long)(c0 + rr) * R + (r0 + cc);
    short hh = f2bf(v);
    ho[o] = hh;
    if (lop) lop[o] = f2bf(v - bf2f(hh));
  }
}

// Elementwise f32 -> bf16 hi (and optional lo residual). n4 = n/4.
__global__ void __launch_bounds__(256) cast_hilo(
    const float* __restrict__ in, short* __restrict__ hi,
    short* __restrict__ lo, long n4) {
  long i = (long)blockIdx.x * 256 + threadIdx.x;
  if (i >= n4) return;
  float4 v = ((const float4*)in)[i];
  s16x4 h;
  h[0] = f2bf(v.x); h[1] = f2bf(v.y); h[2] = f2bf(v.z); h[3] = f2bf(v.w);
  *(s16x4*)(hi + i * 4) = h;
  if (lo) {
    s16x4 L;
    L[0] = f2bf(v.x - bf2f(h[0])); L[1] = f2bf(v.y - bf2f(h[1]));
    L[2] = f2bf(v.z - bf2f(h[2])); L[3] = f2bf(v.w - bf2f(h[3]));
    *(s16x4*)(lo + i * 4) = L;
  }
}

// Column mean of wte (32000x512) -> cm[512]. Grid 125, 256 rows per block.
__global__ void __launch_bounds__(256) colmean_k(const float* __restrict__ wte,
                                                 float* __restrict__ cm) {
  int d = threadIdx.x * 2;
  long r0 = (long)blockIdx.x * 256;
  float a0 = 0.f, a1 = 0.f;
  for (int r = 0; r < 256; r++) {
    float2 v = *(const float2*)(wte + (r0 + r) * 512 + d);
    a0 += v.x; a1 += v.y;
  }
  atomicAdd(&cm[d], a0 * (1.f / 32000.f));
  atomicAdd(&cm[d + 1], a1 * (1.f / 32000.f));
}

// Vm = e - ex_wte (or colmean at layer 0): writes vm32 and vmT16 (b,e,t).
__global__ void __launch_bounds__(256) vm_k(
    const float* __restrict__ e32, const float* __restrict__ exw,
    const float* __restrict__ cm, int useCm, float* __restrict__ vm32,
    short* __restrict__ vmT) {
  int b = blockIdx.z, t0 = blockIdx.y * 64, e0 = blockIdx.x * 64;
  __shared__ short tl[64][72];
  int tid = threadIdx.x;
  long base = ((long)b * 512 + t0) * 512 + e0;
  for (int it = 0; it < 16; ++it) {
    int idx = it * 256 + tid;
    int rr = idx >> 6, cc = idx & 63;
    long o = base + (long)rr * 512 + cc;
    float v = e32[o] - (useCm ? cm[e0 + cc] : exw[o]);
    vm32[o] = v;
    tl[rr][cc] = f2bf(v);
  }
  __syncthreads();
  for (int it = 0; it < 16; ++it) {
    int idx = it * 256 + tid;
    int rr = idx >> 6, cc = idx & 63;
    vmT[((long)b * 512 + (e0 + rr)) * 512 + (t0 + cc)] = tl[cc][rr];
  }
}

// Shadow fp32 path, step 1: delta_last[b, h*512+e] = coef[511]*sum_t krn[h,511,t]*Vm[b,t,e]
__global__ void __launch_bounds__(256) dlast_k(
    const float* __restrict__ krn32, const float* __restrict__ vm32,
    float* __restrict__ dl) {
  int b = blockIdx.x >> 2, h = blockIdx.x & 3;
  int tid = threadIdx.x;
  __shared__ float w[512];
  long kb = ((long)h * 512 + 511) * 512;
  w[tid] = krn32[kb + tid];
  w[tid + 256] = krn32[kb + tid + 256];
  __syncthreads();
  float a0 = 0.f, a1 = 0.f;
  int e0 = tid, e1 = tid + 256;
  const float* vb = vm32 + (long)b * 512 * 512;
  for (int t = 0; t < 512; t++) {
    float wt = w[t];
    a0 += wt * vb[(long)t * 512 + e0];
    a1 += wt * vb[(long)t * 512 + e1];
  }
  dl[(long)b * 2048 + h * 512 + e0] = a0 * (1.f / 512.f);
  dl[(long)b * 2048 + h * 512 + e1] = a1 * (1.f / 512.f);
}

// Shadow step 2: f_last[b,d] += sum_k dl[b,k] * W_o[d,k]   (fp32)
__global__ void __launch_bounds__(256) flast_k(
    const float* __restrict__ dl, const float* __restrict__ Wo,
    float* __restrict__ fl) {
  int b = blockIdx.y, d = blockIdx.x * 256 + threadIdx.x;
  __shared__ float ds_[2048];
  for (int i = threadIdx.x; i < 2048; i += 256) ds_[i] = dl[(long)b * 2048 + i];
  __syncthreads();
  const float* wr = Wo + (long)d * 2048;
  float acc = 0.f;
  for (int k = 0; k < 2048; k += 4) {
    float4 wv = *(const float4*)(wr + k);
    acc += ds_[k] * wv.x + ds_[k + 1] * wv.y + ds_[k + 2] * wv.z +
           ds_[k + 3] * wv.w;
  }
  fl[(long)b * 512 + d] += acc;
}

// logits[b,v] = dot(outln[b,:], wte[v,:]) fp32. One wave handles 16 rows.
__global__ void __launch_bounds__(256) logits_k(
    const float* __restrict__ outln, const float* __restrict__ wte,
    float* __restrict__ out) {
  int tid = threadIdx.x, wave = tid >> 6, lane = tid & 63;
  float o[4][8];
#pragma unroll
  for (int b = 0; b < 4; b++) {
    float4 q0 = *(const float4*)(outln + b * 512 + lane * 8);
    float4 q1 = *(const float4*)(outln + b * 512 + lane * 8 + 4);
    o[b][0] = q0.x; o[b][1] = q0.y; o[b][2] = q0.z; o[b][3] = q0.w;
    o[b][4] = q1.x; o[b][5] = q1.y; o[b][6] = q1.z; o[b][7] = q1.w;
  }
  int vbase = blockIdx.x * 64 + wave * 16;
  for (int i = 0; i < 16; i++) {
    int v = vbase + i;
    const float* row = wte + (long)v * 512 + lane * 8;
    float4 x0 = *(const float4*)row;
    float4 x1 = *(const float4*)(row + 4);
    float xr[8] = {x0.x, x0.y, x0.z, x0.w, x1.x, x1.y, x1.z, x1.w};
    float d0 = 0, d1 = 0, d2 = 0, d3 = 0;
#pragma unroll
    for (int j = 0; j < 8; j++) {
      d0 += o[0][j] * xr[j]; d1 += o[1][j] * xr[j];
      d2 += o[2][j] * xr[j]; d3 += o[3][j] * xr[j];
    }
    for (int off = 32; off > 0; off >>= 1) {
      d0 += __shfl_down(d0, off); d1 += __shfl_down(d1, off);
      d2 += __shfl_down(d2, off); d3 += __shfl_down(d3, off);
    }
    if (lane == 0) {
      out[v] = d0; out[32000 + v] = d1; out[64000 + v] = d2;
      out[96000 + v] = d3;
    }
  }
}

// ---------------------------------------------------------------------------
extern "C" void kernel_launch(void* const* d_in, const int* in_sizes, int n_in,
                              void* d_out, int out_size, void* d_ws,
                              size_t ws_size, hipStream_t stream) {
  (void)in_sizes; (void)n_in; (void)out_size;
  const int* x = (const int*)d_in[0];
  const float* wte = (const float*)d_in[1];
  const float* wpe = (const float*)d_in[2];
  const float* g_e = (const float*)d_in[3];
  const float* g_p = (const float*)d_in[4];
  const float* g_f = (const float*)d_in[5];
  const float* W_q = (const float*)d_in[6];
  const float* W_k = (const float*)d_in[7];
  const float* W_o = (const float*)d_in[8];
  float* out = (float*)d_out;

  char* ws = (char*)d_ws;
  size_t off = 0;
  auto alloc = [&](size_t b) {
    size_t o = off;
    off += (b + 255) & ~(size_t)255;
    return o;
  };
  const long HS = 262144;  // 512*512
  short* wte16 = (short*)(ws + alloc(32000L * 512 * 2));
  short* wteT16 = (short*)(ws + alloc(32000L * 512 * 2));
  // W_q^T and W_k^T contiguous (hi then hi, lo then lo) for the fused launch
  short* wqkt_hi = (short*)(ws + alloc(8L * HS * 2));
  short* wqkt_lo = (short*)(ws + alloc(8L * HS * 2));
  short* wo16 = (short*)(ws + alloc(512L * 2048 * 2));
  short* p_hi = (short*)(ws + alloc(513L * 512 * 2));
  short* p_lo = (short*)(ws + alloc(513L * 512 * 2));
  float* e32 = (float*)(ws + alloc(2048L * 512 * 4));
  float* colmean = (float*)(ws + alloc(512 * 4));
  short* qk_hi = (short*)(ws + alloc(8L * HS * 2));  // Q (4 heads) then K
  short* qk_lo = (short*)(ws + alloc(8L * HS * 2));
  float* sATT = (float*)(ws + alloc(4L * HS * 4));
  float* krn32 = (float*)(ws + alloc(4L * HS * 4));
  short* krn16 = (short*)(ws + alloc(4L * HS * 2));
  short* S16 = (short*)(ws + alloc(2048L * 32000 * 2));
  float* exw32 = (float*)(ws + alloc(2048L * 512 * 4));
  float* vm32 = (float*)(ws + alloc(2048L * 512 * 4));
  short* vmT16 = (short*)(ws + alloc(2048L * 512 * 2));
  short* delta16 = (short*)(ws + alloc(2048L * 2048 * 2));
  float* fk32 = (float*)(ws + alloc(2048L * 512 * 4));
  short* fk16 = (short*)(ws + alloc(2048L * 512 * 2));
  float* flast = (float*)(ws + alloc(4L * 512 * 4));
  float* dl = (float*)(ws + alloc(4L * 2048 * 4));
  float* outln = (float*)(ws + alloc(4L * 512 * 4));
  if (off > ws_size) return;  // ws too small: bail (out stays zero)

  // --- zero accumulators ---
  hipMemsetAsync(colmean, 0, 512 * 4, stream);
  hipMemsetAsync(fk32, 0, 2048L * 512 * 4, stream);
  hipMemsetAsync(flast, 0, 4L * 512 * 4, stream);

  // --- setup casts / transposes ---
  cast_hilo<<<16000, 256, 0, stream>>>(wte, wte16, nullptr, 32000L * 512 / 4);
  colmean_k<<<125, 256, 0, stream>>>(wte, colmean);
  transpose_cast<<<dim3(8, 500, 1), 256, 0, stream>>>(wte, wteT16, nullptr,
                                                      32000, 512);
  transpose_cast<<<dim3(8, 8, 4), 256, 0, stream>>>(W_q, wqkt_hi, wqkt_lo, 512,
                                                    512);
  transpose_cast<<<dim3(8, 8, 4), 256, 0, stream>>>(
      W_k, wqkt_hi + 4 * HS, wqkt_lo + 4 * HS, 512, 512);
  cast_hilo<<<1024, 256, 0, stream>>>(W_o, wo16, nullptr, 512L * 2048 / 4);
  ln_rows<<<2048, 256, 0, stream>>>(nullptr, x, wte, g_e, e32, nullptr, nullptr,
                                    0);
  ln_rows<<<513, 256, 0, stream>>>(wpe, nullptr, nullptr, g_p, nullptr, p_hi,
                                   p_lo, 1);

  // --- Q|K = x_j|x_i @ W_q|W_k, one fused 3-term launch, direct hi/lo out ---
  // z = zq*4 + head; zq=0 -> Q (A = p+512), zq=1 -> K (A = p).
  gemm_nt<4, 3><<<dim3(4, 4, 8), 256, 0, stream>>>(
      p_hi + 512, wqkt_hi, p_lo + 512, wqkt_lo, qk_hi, qk_lo, 512, 512, 512,
      512, 0, 4, /*sAq*/ -512, /*sAr*/ 0, /*sBq*/ 4 * HS, /*sBr*/ HS,
      /*sCq*/ 4 * HS, /*sCr*/ HS);
  // raw attention scores = Q @ K^T, one fused 3-term launch
  gemm_nt<3, 3><<<dim3(4, 4, 4), 256, 0, stream>>>(
      qk_hi, qk_hi + 4 * HS, qk_lo, qk_lo + 4 * HS, sATT, nullptr, 512, 512,
      512, 512, 0, 4, 0, HS, 0, HS, 0, HS);
  softmax_krn_k<<<2048, 256, 0, stream>>>(sATT, krn32, krn16);

  // --- layer loop ---
  for (int l = 0; l < 4; ++l) {
    if (l > 0) {
      // scores = f_k @ wte^T  (M=2048, N=32000, K=512), raw bf16
      gemm_nt<0, 1><<<dim3(16, 250, 1), 256, 0, stream>>>(
          fk16, wte16, nullptr, nullptr, S16, nullptr, 512, 512, 32000, 512, 0,
          1, 0, 0, 0, 0, 0, 0);
      softmax_vocab<<<2048, 256, 0, stream>>>(S16);
      hipMemsetAsync(exw32, 0, 2048L * 512 * 4, stream);
      // ex_wte = P @ wte  (M=2048, N=512, K=32000), split-K=10, fp32 atomics
      gemm_nt<1, 1><<<dim3(16, 4, 10), 256, 0, stream>>>(
          S16, wteT16, nullptr, nullptr, exw32, nullptr, 32000, 32000, 512,
          3200, 3200, 10, 0, 0, 0, 0, 0, 0);
    }
    vm_k<<<dim3(8, 8, 4), 256, 0, stream>>>(e32, exw32, colmean,
                                            (l == 0) ? 1 : 0, vm32, vmT16);
    // delta[b,h] = krn[h] @ Vm[b], scaled by coef[s], packed (b,s,h*512+e)
    gemm_nt<2, 1><<<dim3(4, 4, 16), 256, 0, stream>>>(
        krn16, vmT16, nullptr, nullptr, delta16, nullptr, 512, 512, 2048, 512,
        0, 4, 0, HS, HS, 0, 1048576L, 512);
    // f_k += delta @ W_o^T  (M=2048, N=512, K=2048), split-K=4
    gemm_nt<1, 1><<<dim3(16, 4, 4), 256, 0, stream>>>(
        delta16, wo16, nullptr, nullptr, fk32, nullptr, 2048, 2048, 512, 512,
        512, 4, 0, 0, 0, 0, 0, 0);
    // fp32 shadow path for the last position
    dlast_k<<<16, 256, 0, stream>>>(krn32, vm32, dl);
    flast_k<<<dim3(2, 4, 1), 256, 0, stream>>>(dl, W_o, flast);
    cast_hilo<<<1024, 256, 0, stream>>>(fk32, fk16, nullptr, 262144);
  }

  // --- final LN + logits (pure fp32) ---
  ln_rows<<<4, 256, 0, stream>>>(flast, nullptr, nullptr, g_f, outln, nullptr,
                                 nullptr, 2);
  logits_k<<<500, 256, 0, stream>>>(outln, wte, out);
}

// Round 4
// 1482.295 us; speedup vs baseline: 1.2053x; 1.0245x over previous
//
#include <hip/hip_runtime.h>
#include <stdint.h>

// ---------------------------------------------------------------------------
// Shapes (fixed by the reference): V=32000, D=512, H=4, L=4, B=4, S=512
// Output: logits (4,1,32000) fp32.
// Strategy:
//  - bf16 MFMA for the big vocab GEMMs (error damped by softmax over 32000).
//  - split-bf16 (hi/lo, 3-term) MFMA for Q/K/krn (near-fp32 accuracy).
//  - fp32 shadow path for f_k[:,511,:] (the only row that reaches the output;
//    final LN amplifies by ~316 since var(f_k_last) << eps).
//  - layer 0: softmax(0) is uniform -> ex_wte = colmean(wte) exactly.
//  - R2: BK=64, XOR-swizzled LDS (bank conflicts: 8.19M -> 0), DMA staging.
//  - R4: softmax fused away: scores epilogue stores exp(S) bf16 + row-sums L
//    via wave-reduce+atomic (|S|<<1 so no max needed); vm_k divides by L.
//    ex_wte split-K 20 (5 blocks/CU).
// ---------------------------------------------------------------------------

typedef __attribute__((ext_vector_type(8))) short s16x8;
typedef __attribute__((ext_vector_type(4))) short s16x4;
typedef __attribute__((ext_vector_type(4))) float f32x4;

__device__ __forceinline__ short f2bf(float f) {
  unsigned u = __float_as_uint(f);
  unsigned r = (u + 0x7FFFu + ((u >> 16) & 1u)) >> 16;  // RNE
  return (short)r;
}
__device__ __forceinline__ float bf2f(short u) {
  unsigned v = ((unsigned)(unsigned short)u) << 16;
  return __uint_as_float(v);
}

// Async global->LDS DMA, 16B per lane. LDS dest = wave-uniform base + lane*16.
__device__ __forceinline__ void load16(const short* g, short* l) {
  __builtin_amdgcn_global_load_lds(
      (__attribute__((address_space(1))) void*)(short*)g,
      (__attribute__((address_space(3))) void*)l, 16, 0, 0);
}

// ---------------------------------------------------------------------------
// Generic NT GEMM: C[m,n] (+)= sum_k A[m,k] * B[n,k], A (MxK), B (NxK) bf16.
// 128x128 tile, BK=64, 256 threads (4 waves, each 64x64 via 4x4 mfma 16x16x32).
// LDS layout swizzled: (row r, 16B-granule g) lives at r*128B + ((g^(r&7))*16B)
// -> staging is contiguous per lane (DMA-safe), fragment ds_read_b128 is
// 2-way-aliased only (free per m136).
// z-dim: zq=z/zdiv, zr=z%zdiv. Batch strides in *elements*. k0 = zr*k0_mul.
// TERMS=3: accumulate Ag*Bg + Ag*B2g + A2g*Bg (split-bf16 hi/lo 3-term).
// EPI: 0 = store bf16; 1 = atomicAdd fp32; 2 = bf16 scaled by 1/(1+row);
//      3 = plain fp32 store; 4 = store bf16 hi to Cg and lo residual to C2g;
//      5 = store bf16 exp(v) to Cg, atomicAdd row-sums of exp to (float*)C2g.
// ---------------------------------------------------------------------------
template <int EPI, int TERMS>
__global__ void __launch_bounds__(256) gemm_nt(
    const short* __restrict__ Ag, const short* __restrict__ Bg,
    const short* __restrict__ A2g, const short* __restrict__ B2g,
    void* __restrict__ Cg, short* __restrict__ C2g, int lda, int ldb, int ldc,
    int klen, int k0_mul, int zdiv, long sAq, long sAr, long sBq, long sBr,
    long sCq, long sCr) {
  const int tid = threadIdx.x;
  const int z = blockIdx.z;
  const int zq = z / zdiv, zr = z % zdiv;
  const long aOff = zq * sAq + zr * sAr + (long)zr * k0_mul;
  const long bOff = zq * sBq + zr * sBr + (long)zr * k0_mul;
  const long cOff = zq * sCq + zr * sCr;

  __shared__ __align__(16) short As[128 * 64];
  __shared__ __align__(16) short Bs[128 * 64];

  const long m0 = (long)blockIdx.x * 128;
  const long n0 = (long)blockIdx.y * 128;

  const int wave = tid >> 6, lane = tid & 63;
  const int wm = (wave >> 1) * 64, wn = (wave & 1) * 64;
  const int mlan = lane & 15, kg = lane >> 4;

  f32x4 acc[4][4] = {};

  // staging: per wave 32 rows of A and 32 rows of B, 4 DMA instrs each.
  const int g_src = ((lane & 7) ^ (lane >> 3)) * 8;  // element offset
  const int lrow = lane >> 3;                        // 0..7
  short* lA = As + wave * 2048 + lane * 8;
  short* lB = Bs + wave * 2048 + lane * 8;

  // fragment read swizzle: row&7 == mlan&7.
  const int gi0 = ((kg ^ (mlan & 7)) * 8);
  const int gi1 = gi0 ^ 32;

  const int nk = klen >> 6;
#pragma unroll 1
  for (int t = 0; t < TERMS; ++t) {
    const short* Abase = ((TERMS == 3 && t == 2) ? A2g : Ag) + aOff;
    const short* Bbase = ((TERMS == 3 && t == 1) ? B2g : Bg) + bOff;
    const short* ga = Abase + (m0 + wave * 32 + lrow) * (long)lda + g_src;
    const short* gb = Bbase + (n0 + wave * 32 + lrow) * (long)ldb + g_src;
#pragma unroll 1
    for (int kt = 0; kt < nk; ++kt) {
      const int kb = kt * 64;
      __syncthreads();
      load16(ga + kb, lA);
      load16(ga + 8 * (long)lda + kb, lA + 512);
      load16(ga + 16 * (long)lda + kb, lA + 1024);
      load16(ga + 24 * (long)lda + kb, lA + 1536);
      load16(gb + kb, lB);
      load16(gb + 8 * (long)ldb + kb, lB + 512);
      load16(gb + 16 * (long)ldb + kb, lB + 1024);
      load16(gb + 24 * (long)ldb + kb, lB + 1536);
      __syncthreads();
      s16x8 af[2][4], bq[2][4];
      const short* pA = As + (wm + mlan) * 64;
      const short* pB = Bs + (wn + mlan) * 64;
#pragma unroll
      for (int i = 0; i < 4; ++i) {
        af[0][i] = *(const s16x8*)(pA + i * 1024 + gi0);
        af[1][i] = *(const s16x8*)(pA + i * 1024 + gi1);
        bq[0][i] = *(const s16x8*)(pB + i * 1024 + gi0);
        bq[1][i] = *(const s16x8*)(pB + i * 1024 + gi1);
      }
#pragma unroll
      for (int h = 0; h < 2; ++h)
#pragma unroll
        for (int mi = 0; mi < 4; ++mi)
#pragma unroll
          for (int ni = 0; ni < 4; ++ni)
            acc[mi][ni] = __builtin_amdgcn_mfma_f32_16x16x32_bf16(
                af[h][mi], bq[h][ni], acc[mi][ni], 0, 0, 0);
    }
  }

  const int rq = (lane >> 4) * 4;
  if (EPI == 5) {
    // exp epilogue + per-row sums (no max needed: |S| << 1).
#pragma unroll
    for (int mi = 0; mi < 4; ++mi) {
#pragma unroll
      for (int r = 0; r < 4; ++r) {
        long row = m0 + wm + mi * 16 + rq + r;
        float s = 0.f;
#pragma unroll
        for (int ni = 0; ni < 4; ++ni) {
          long col = n0 + wn + ni * 16 + mlan;
          float v = __expf(acc[mi][ni][r]);
          ((short*)Cg)[cOff + row * (long)ldc + col] = f2bf(v);
          s += v;
        }
        s += __shfl_xor(s, 1);
        s += __shfl_xor(s, 2);
        s += __shfl_xor(s, 4);
        s += __shfl_xor(s, 8);
        if (mlan == 0) atomicAdd((float*)C2g + row, s);
      }
    }
    return;
  }
#pragma unroll
  for (int mi = 0; mi < 4; ++mi) {
#pragma unroll
    for (int ni = 0; ni < 4; ++ni) {
#pragma unroll
      for (int r = 0; r < 4; ++r) {
        long row = m0 + wm + mi * 16 + rq + r;   // M index
        long col = n0 + wn + ni * 16 + mlan;     // N index
        float v = acc[mi][ni][r];
        long o = cOff + row * (long)ldc + col;
        if (EPI == 1) {
          atomicAdd((float*)Cg + o, v);
        } else if (EPI == 3) {
          ((float*)Cg)[o] = v;
        } else if (EPI == 4) {
          short h = f2bf(v);
          ((short*)Cg)[o] = h;
          C2g[o] = f2bf(v - bf2f(h));
        } else {
          if (EPI == 2) v *= 1.0f / (1.0f + (float)row);
          ((short*)Cg)[o] = f2bf(v);
        }
      }
    }
  }
}

// ---------------------------------------------------------------------------
// LayerNorm of 512-wide rows. mode 0: gather wte[x[r]] -> o32 (e).
// mode 1: src rows -> hi/lo bf16 (p). mode 2: src rows -> o32 (final LN).
// ---------------------------------------------------------------------------
__global__ void __launch_bounds__(256) ln_rows(
    const float* __restrict__ src, const int* __restrict__ tok,
    const float* __restrict__ wte, const float* __restrict__ g,
    float* __restrict__ o32, short* __restrict__ ohi, short* __restrict__ olo,
    int mode) {
  int r = blockIdx.x, tid = threadIdx.x;
  const float* in;
  if (mode == 0)
    in = wte + (long)tok[r] * 512;
  else
    in = src + (long)r * 512;
  int d = tid * 2;
  float2 v = *(const float2*)(in + d);
  float s1 = v.x + v.y;
  float s2 = v.x * v.x + v.y * v.y;
  __shared__ float red[20];
  for (int o = 32; o > 0; o >>= 1) {
    s1 += __shfl_down(s1, o);
    s2 += __shfl_down(s2, o);
  }
  int wave = tid >> 6, lane = tid & 63;
  if (lane == 0) { red[wave] = s1; red[wave + 8] = s2; }
  __syncthreads();
  if (tid == 0) {
    float a = red[0] + red[1] + red[2] + red[3];
    float b = red[8] + red[9] + red[10] + red[11];
    float mean = a * (1.f / 512.f);
    float var = b * (1.f / 512.f) - mean * mean;
    red[16] = mean;
    red[17] = 1.0f / sqrtf(var + 1e-5f);
  }
  __syncthreads();
  float mean = red[16], rs = red[17];
  float2 gg = *(const float2*)(g + d);
  float y0 = (v.x - mean) * rs * gg.x;
  float y1 = (v.y - mean) * rs * gg.y;
  long o = (long)r * 512 + d;
  if (o32) { o32[o] = y0; o32[o + 1] = y1; }
  if (ohi) {
    short h0 = f2bf(y0), h1 = f2bf(y1);
    ohi[o] = h0; ohi[o + 1] = h1;
    if (olo) {
      olo[o] = f2bf(y0 - bf2f(h0));
      olo[o + 1] = f2bf(y1 - bf2f(h1));
    }
  }
}

// Attention softmax: raw (H,S,S) fp32 -> scale, clip(+-10), causal, softmax.
__global__ void __launch_bounds__(256) softmax_krn_k(
    const float* __restrict__ raw, float* __restrict__ k32,
    short* __restrict__ k16) {
  int bx = blockIdx.x;
  int h = bx >> 9, s = bx & 511;
  long base = ((long)h * 512 + s) * 512;
  int tid = threadIdx.x;
  const float scale = 0.04419417382415922f;  // 1/sqrt(512)
  float e0 = 0.f, e1 = 0.f, l = 0.f;
  int t0 = tid, t1 = tid + 256;
  if (t0 <= s) {
    float v = raw[base + t0] * scale;
    v = fminf(fmaxf(v, -10.f), 10.f);
    e0 = __expf(v); l += e0;
  }
  if (t1 <= s) {
    float v = raw[base + t1] * scale;
    v = fminf(fmaxf(v, -10.f), 10.f);
    e1 = __expf(v); l += e1;
  }
  for (int o = 32; o > 0; o >>= 1) l += __shfl_down(l, o);
  __shared__ float red[10];
  int wave = tid >> 6, lane = tid & 63;
  if (lane == 0) red[wave] = l;
  __syncthreads();
  if (tid == 0) red[8] = 1.0f / (red[0] + red[1] + red[2] + red[3]);
  __syncthreads();
  float inv = red[8];
  k32[base + t0] = e0 * inv;
  k16[base + t0] = f2bf(e0 * inv);
  k32[base + t1] = e1 * inv;
  k16[base + t1] = f2bf(e1 * inv);
}

// Transpose+cast: in (RxC) f32 -> out (CxR) bf16 hi (and optional lo).
__global__ void __launch_bounds__(256) transpose_cast(
    const float* __restrict__ in, short* __restrict__ hi,
    short* __restrict__ lo, int R, int C) {
  long bo = (long)blockIdx.z * R * C;
  const float* inp = in + bo;
  short* ho = hi + bo;
  short* lop = lo ? lo + bo : nullptr;
  int c0 = blockIdx.x * 64, r0 = blockIdx.y * 64;
  __shared__ float tl[64][65];
  int tid = threadIdx.x;
  for (int it = 0; it < 16; ++it) {
    int idx = it * 256 + tid;
    int rr = idx >> 6, cc = idx & 63;
    tl[rr][cc] = inp[(long)(r0 + rr) * C + (c0 + cc)];
  }
  __syncthreads();
  for (int it = 0; it < 16; ++it) {
    int idx = it * 256 + tid;
    int rr = idx >> 6, cc = idx & 63;
    float v = tl[cc][rr];
    long o = (long)(c0 + rr) * R + (r0 + cc);
    short hh = f2bf(v);
    ho[o] = hh;
    if (lop) lop[o] = f2bf(v - bf2f(hh));
  }
}

// Elementwise f32 -> bf16 hi (and optional lo residual). n4 = n/4.
__global__ void __launch_bounds__(256) cast_hilo(
    const float* __restrict__ in, short* __restrict__ hi,
    short* __restrict__ lo, long n4) {
  long i = (long)blockIdx.x * 256 + threadIdx.x;
  if (i >= n4) return;
  float4 v = ((const float4*)in)[i];
  s16x4 h;
  h[0] = f2bf(v.x); h[1] = f2bf(v.y); h[2] = f2bf(v.z); h[3] = f2bf(v.w);
  *(s16x4*)(hi + i * 4) = h;
  if (lo) {
    s16x4 L;
    L[0] = f2bf(v.x - bf2f(h[0])); L[1] = f2bf(v.y - bf2f(h[1]));
    L[2] = f2bf(v.z - bf2f(h[2])); L[3] = f2bf(v.w - bf2f(h[3]));
    *(s16x4*)(lo + i * 4) = L;
  }
}

// Column mean of wte (32000x512) -> cm[512]. Grid 125, 256 rows per block.
__global__ void __launch_bounds__(256) colmean_k(const float* __restrict__ wte,
                                                 float* __restrict__ cm) {
  int d = threadIdx.x * 2;
  long r0 = (long)blockIdx.x * 256;
  float a0 = 0.f, a1 = 0.f;
  for (int r = 0; r < 256; r++) {
    float2 v = *(const float2*)(wte + (r0 + r) * 512 + d);
    a0 += v.x; a1 += v.y;
  }
  atomicAdd(&cm[d], a0 * (1.f / 32000.f));
  atomicAdd(&cm[d + 1], a1 * (1.f / 32000.f));
}

// Vm = e - exw/L (or e - colmean at layer 0): writes vm32 and vmT16 (b,e,t).
__global__ void __launch_bounds__(256) vm_k(
    const float* __restrict__ e32, const float* __restrict__ exw,
    const float* __restrict__ cm, const float* __restrict__ Lrow, int useCm,
    float* __restrict__ vm32, short* __restrict__ vmT) {
  int b = blockIdx.z, t0 = blockIdx.y * 64, e0 = blockIdx.x * 64;
  __shared__ short tl[64][72];
  int tid = threadIdx.x;
  long base = ((long)b * 512 + t0) * 512 + e0;
  for (int it = 0; it < 16; ++it) {
    int idx = it * 256 + tid;
    int rr = idx >> 6, cc = idx & 63;
    long o = base + (long)rr * 512 + cc;
    float v;
    if (useCm) {
      v = e32[o] - cm[e0 + cc];
    } else {
      float inv = 1.0f / Lrow[b * 512 + t0 + rr];
      v = e32[o] - exw[o] * inv;
    }
    vm32[o] = v;
    tl[rr][cc] = f2bf(v);
  }
  __syncthreads();
  for (int it = 0; it < 16; ++it) {
    int idx = it * 256 + tid;
    int rr = idx >> 6, cc = idx & 63;
    vmT[((long)b * 512 + (e0 + rr)) * 512 + (t0 + cc)] = tl[cc][rr];
  }
}

// Shadow fp32 path, step 1: delta_last[b, h*512+e] = coef[511]*sum_t krn[h,511,t]*Vm[b,t,e]
__global__ void __launch_bounds__(256) dlast_k(
    const float* __restrict__ krn32, const float* __restrict__ vm32,
    float* __restrict__ dl) {
  int b = blockIdx.x >> 2, h = blockIdx.x & 3;
  int tid = threadIdx.x;
  __shared__ float w[512];
  long kb = ((long)h * 512 + 511) * 512;
  w[tid] = krn32[kb + tid];
  w[tid + 256] = krn32[kb + tid + 256];
  __syncthreads();
  float a0 = 0.f, a1 = 0.f;
  int e0 = tid, e1 = tid + 256;
  const float* vb = vm32 + (long)b * 512 * 512;
  for (int t = 0; t < 512; t++) {
    float wt = w[t];
    a0 += wt * vb[(long)t * 512 + e0];
    a1 += wt * vb[(long)t * 512 + e1];
  }
  dl[(long)b * 2048 + h * 512 + e0] = a0 * (1.f / 512.f);
  dl[(long)b * 2048 + h * 512 + e1] = a1 * (1.f / 512.f);
}

// Shadow step 2: f_last[b,d] += sum_k dl[b,k] * W_o[d,k]   (fp32)
__global__ void __launch_bounds__(256) flast_k(
    const float* __restrict__ dl, const float* __restrict__ Wo,
    float* __restrict__ fl) {
  int b = blockIdx.y, d = blockIdx.x * 256 + threadIdx.x;
  __shared__ float ds_[2048];
  for (int i = threadIdx.x; i < 2048; i += 256) ds_[i] = dl[(long)b * 2048 + i];
  __syncthreads();
  const float* wr = Wo + (long)d * 2048;
  float acc = 0.f;
  for (int k = 0; k < 2048; k += 4) {
    float4 wv = *(const float4*)(wr + k);
    acc += ds_[k] * wv.x + ds_[k + 1] * wv.y + ds_[k + 2] * wv.z +
           ds_[k + 3] * wv.w;
  }
  fl[(long)b * 512 + d] += acc;
}

// logits[b,v] = dot(outln[b,:], wte[v,:]) fp32. One wave handles 16 rows.
__global__ void __launch_bounds__(256) logits_k(
    const float* __restrict__ outln, const float* __restrict__ wte,
    float* __restrict__ out) {
  int tid = threadIdx.x, wave = tid >> 6, lane = tid & 63;
  float o[4][8];
#pragma unroll
  for (int b = 0; b < 4; b++) {
    float4 q0 = *(const float4*)(outln + b * 512 + lane * 8);
    float4 q1 = *(const float4*)(outln + b * 512 + lane * 8 + 4);
    o[b][0] = q0.x; o[b][1] = q0.y; o[b][2] = q0.z; o[b][3] = q0.w;
    o[b][4] = q1.x; o[b][5] = q1.y; o[b][6] = q1.z; o[b][7] = q1.w;
  }
  int vbase = blockIdx.x * 64 + wave * 16;
  for (int i = 0; i < 16; i++) {
    int v = vbase + i;
    const float* row = wte + (long)v * 512 + lane * 8;
    float4 x0 = *(const float4*)row;
    float4 x1 = *(const float4*)(row + 4);
    float xr[8] = {x0.x, x0.y, x0.z, x0.w, x1.x, x1.y, x1.z, x1.w};
    float d0 = 0, d1 = 0, d2 = 0, d3 = 0;
#pragma unroll
    for (int j = 0; j < 8; j++) {
      d0 += o[0][j] * xr[j]; d1 += o[1][j] * xr[j];
      d2 += o[2][j] * xr[j]; d3 += o[3][j] * xr[j];
    }
    for (int off = 32; off > 0; off >>= 1) {
      d0 += __shfl_down(d0, off); d1 += __shfl_down(d1, off);
      d2 += __shfl_down(d2, off); d3 += __shfl_down(d3, off);
    }
    if (lane == 0) {
      out[v] = d0; out[32000 + v] = d1; out[64000 + v] = d2;
      out[96000 + v] = d3;
    }
  }
}

// ---------------------------------------------------------------------------
extern "C" void kernel_launch(void* const* d_in, const int* in_sizes, int n_in,
                              void* d_out, int out_size, void* d_ws,
                              size_t ws_size, hipStream_t stream) {
  (void)in_sizes; (void)n_in; (void)out_size;
  const int* x = (const int*)d_in[0];
  const float* wte = (const float*)d_in[1];
  const float* wpe = (const float*)d_in[2];
  const float* g_e = (const float*)d_in[3];
  const float* g_p = (const float*)d_in[4];
  const float* g_f = (const float*)d_in[5];
  const float* W_q = (const float*)d_in[6];
  const float* W_k = (const float*)d_in[7];
  const float* W_o = (const float*)d_in[8];
  float* out = (float*)d_out;

  char* ws = (char*)d_ws;
  size_t off = 0;
  auto alloc = [&](size_t b) {
    size_t o = off;
    off += (b + 255) & ~(size_t)255;
    return o;
  };
  const long HS = 262144;  // 512*512
  short* wte16 = (short*)(ws + alloc(32000L * 512 * 2));
  short* wteT16 = (short*)(ws + alloc(32000L * 512 * 2));
  // W_q^T and W_k^T contiguous (hi then hi, lo then lo) for the fused launch
  short* wqkt_hi = (short*)(ws + alloc(8L * HS * 2));
  short* wqkt_lo = (short*)(ws + alloc(8L * HS * 2));
  short* wo16 = (short*)(ws + alloc(512L * 2048 * 2));
  short* p_hi = (short*)(ws + alloc(513L * 512 * 2));
  short* p_lo = (short*)(ws + alloc(513L * 512 * 2));
  float* e32 = (float*)(ws + alloc(2048L * 512 * 4));
  float* colmean = (float*)(ws + alloc(512 * 4));
  short* qk_hi = (short*)(ws + alloc(8L * HS * 2));  // Q (4 heads) then K
  short* qk_lo = (short*)(ws + alloc(8L * HS * 2));
  float* sATT = (float*)(ws + alloc(4L * HS * 4));
  float* krn32 = (float*)(ws + alloc(4L * HS * 4));
  short* krn16 = (short*)(ws + alloc(4L * HS * 2));
  short* S16 = (short*)(ws + alloc(2048L * 32000 * 2));
  float* Lrow = (float*)(ws + alloc(2048L * 4));
  float* exw32 = (float*)(ws + alloc(2048L * 512 * 4));
  float* vm32 = (float*)(ws + alloc(2048L * 512 * 4));
  short* vmT16 = (short*)(ws + alloc(2048L * 512 * 2));
  short* delta16 = (short*)(ws + alloc(2048L * 2048 * 2));
  float* fk32 = (float*)(ws + alloc(2048L * 512 * 4));
  short* fk16 = (short*)(ws + alloc(2048L * 512 * 2));
  float* flast = (float*)(ws + alloc(4L * 512 * 4));
  float* dl = (float*)(ws + alloc(4L * 2048 * 4));
  float* outln = (float*)(ws + alloc(4L * 512 * 4));
  if (off > ws_size) return;  // ws too small: bail (out stays zero)

  // --- zero accumulators ---
  hipMemsetAsync(colmean, 0, 512 * 4, stream);
  hipMemsetAsync(fk32, 0, 2048L * 512 * 4, stream);
  hipMemsetAsync(flast, 0, 4L * 512 * 4, stream);

  // --- setup casts / transposes ---
  cast_hilo<<<16000, 256, 0, stream>>>(wte, wte16, nullptr, 32000L * 512 / 4);
  colmean_k<<<125, 256, 0, stream>>>(wte, colmean);
  transpose_cast<<<dim3(8, 500, 1), 256, 0, stream>>>(wte, wteT16, nullptr,
                                                      32000, 512);
  transpose_cast<<<dim3(8, 8, 4), 256, 0, stream>>>(W_q, wqkt_hi, wqkt_lo, 512,
                                                    512);
  transpose_cast<<<dim3(8, 8, 4), 256, 0, stream>>>(
      W_k, wqkt_hi + 4 * HS, wqkt_lo + 4 * HS, 512, 512);
  cast_hilo<<<1024, 256, 0, stream>>>(W_o, wo16, nullptr, 512L * 2048 / 4);
  ln_rows<<<2048, 256, 0, stream>>>(nullptr, x, wte, g_e, e32, nullptr, nullptr,
                                    0);
  ln_rows<<<513, 256, 0, stream>>>(wpe, nullptr, nullptr, g_p, nullptr, p_hi,
                                   p_lo, 1);

  // --- Q|K = x_j|x_i @ W_q|W_k, one fused 3-term launch, direct hi/lo out ---
  // z = zq*4 + head; zq=0 -> Q (A = p+512), zq=1 -> K (A = p).
  gemm_nt<4, 3><<<dim3(4, 4, 8), 256, 0, stream>>>(
      p_hi + 512, wqkt_hi, p_lo + 512, wqkt_lo, qk_hi, qk_lo, 512, 512, 512,
      512, 0, 4, /*sAq*/ -512, /*sAr*/ 0, /*sBq*/ 4 * HS, /*sBr*/ HS,
      /*sCq*/ 4 * HS, /*sCr*/ HS);
  // raw attention scores = Q @ K^T, one fused 3-term launch
  gemm_nt<3, 3><<<dim3(4, 4, 4), 256, 0, stream>>>(
      qk_hi, qk_hi + 4 * HS, qk_lo, qk_lo + 4 * HS, sATT, nullptr, 512, 512,
      512, 512, 0, 4, 0, HS, 0, HS, 0, HS);
  softmax_krn_k<<<2048, 256, 0, stream>>>(sATT, krn32, krn16);

  // --- layer loop ---
  for (int l = 0; l < 4; ++l) {
    if (l > 0) {
      hipMemsetAsync(Lrow, 0, 2048L * 4, stream);
      // S16 = exp(f_k @ wte^T), Lrow = row sums  (M=2048, N=32000, K=512)
      gemm_nt<5, 1><<<dim3(16, 250, 1), 256, 0, stream>>>(
          fk16, wte16, nullptr, nullptr, S16, (short*)Lrow, 512, 512, 32000,
          512, 0, 1, 0, 0, 0, 0, 0, 0);
      hipMemsetAsync(exw32, 0, 2048L * 512 * 4, stream);
      // exw = expS @ wte  (M=2048, N=512, K=32000), split-K=20, fp32 atomics
      gemm_nt<1, 1><<<dim3(16, 4, 20), 256, 0, stream>>>(
          S16, wteT16, nullptr, nullptr, exw32, nullptr, 32000, 32000, 512,
          1600, 1600, 20, 0, 0, 0, 0, 0, 0);
    }
    vm_k<<<dim3(8, 8, 4), 256, 0, stream>>>(e32, exw32, colmean, Lrow,
                                            (l == 0) ? 1 : 0, vm32, vmT16);
    // delta[b,h] = krn[h] @ Vm[b], scaled by coef[s], packed (b,s,h*512+e)
    gemm_nt<2, 1><<<dim3(4, 4, 16), 256, 0, stream>>>(
        krn16, vmT16, nullptr, nullptr, delta16, nullptr, 512, 512, 2048, 512,
        0, 4, 0, HS, HS, 0, 1048576L, 512);
    // f_k += delta @ W_o^T  (M=2048, N=512, K=2048), split-K=4
    gemm_nt<1, 1><<<dim3(16, 4, 4), 256, 0, stream>>>(
        delta16, wo16, nullptr, nullptr, fk32, nullptr, 2048, 2048, 512, 512,
        512, 4, 0, 0, 0, 0, 0, 0);
    // fp32 shadow path for the last position
    dlast_k<<<16, 256, 0, stream>>>(krn32, vm32, dl);
    flast_k<<<dim3(2, 4, 1), 256, 0, stream>>>(dl, W_o, flast);
    cast_hilo<<<1024, 256, 0, stream>>>(fk32, fk16, nullptr, 262144);
  }

  // --- final LN + logits (pure fp32) ---
  ln_rows<<<4, 256, 0, stream>>>(flast, nullptr, nullptr, g_f, outln, nullptr,
                                 nullptr, 2);
  logits_k<<<500, 256, 0, stream>>>(outln, wte, out);
}

// Round 5
// 1051.058 us; speedup vs baseline: 1.6998x; 1.4103x over previous
//
#include <hip/hip_runtime.h>
#include <stdint.h>

// ---------------------------------------------------------------------------
// Shapes: V=32000, D=512, H=4, L=4, B=4, S=512. Output logits (4,1,32000) f32.
//  - bf16 MFMA vocab GEMMs (softmax damps bf16 noise).
//  - split-bf16 3-term MFMA for Q/K/QK^T (near-fp32 krn).
//  - fp32 shadow path for f_k[:,511,:] (only row reaching output; final LN
//    amplifies ~316x).
//  - layer 0: softmax(0) uniform -> ex_wte = colmean(wte) exactly.
//  - R2: BK=64, XOR-swizzled LDS (conflicts 8.19M -> 0), 16B DMA staging.
//  - R4: vocab softmax fused into scores epilogue (exp + row-sum atomics).
//  - R5: NO atomics in big GEMMs: ex_wte + fk use bf16 partial slabs reduced
//    downstream; dlast fused into vm_k; flast on WoT (coalesced); layer 3
//    skips the dead bulk-f_k path. Partials alias dead setup buffers.
// ---------------------------------------------------------------------------

typedef __attribute__((ext_vector_type(8))) short s16x8;
typedef __attribute__((ext_vector_type(4))) short s16x4;
typedef __attribute__((ext_vector_type(4))) float f32x4;

__device__ __forceinline__ short f2bf(float f) {
  unsigned u = __float_as_uint(f);
  unsigned r = (u + 0x7FFFu + ((u >> 16) & 1u)) >> 16;  // RNE
  return (short)r;
}
__device__ __forceinline__ float bf2f(short u) {
  unsigned v = ((unsigned)(unsigned short)u) << 16;
  return __uint_as_float(v);
}

__device__ __forceinline__ void load16(const short* g, short* l) {
  __builtin_amdgcn_global_load_lds(
      (__attribute__((address_space(1))) void*)(short*)g,
      (__attribute__((address_space(3))) void*)l, 16, 0, 0);
}

// ---------------------------------------------------------------------------
// NT GEMM: C[m,n] (+)= sum_k A[m,k]*B[n,k]. 128x128 tile, BK=64, 4 waves.
// XOR-swizzled LDS; global_load_lds staging. z: zq=z/zdiv, zr=z%zdiv;
// k0 = zr*k0_mul applied to A and B. TERMS=3: hi*hi + hi*lo + lo*hi.
// EPI: 0 bf16 store; 1 atomicAdd f32; 2 bf16 * 1/(1+row); 3 f32 store;
//      4 bf16 hi->Cg, lo->C2g; 5 bf16 exp(v)->Cg + row-sum atomics->C2g.
// ---------------------------------------------------------------------------
template <int EPI, int TERMS>
__global__ void __launch_bounds__(256) gemm_nt(
    const short* __restrict__ Ag, const short* __restrict__ Bg,
    const short* __restrict__ A2g, const short* __restrict__ B2g,
    void* __restrict__ Cg, short* __restrict__ C2g, int lda, int ldb, int ldc,
    int klen, int k0_mul, int zdiv, long sAq, long sAr, long sBq, long sBr,
    long sCq, long sCr) {
  const int tid = threadIdx.x;
  const int z = blockIdx.z;
  const int zq = z / zdiv, zr = z % zdiv;
  const long aOff = zq * sAq + zr * sAr + (long)zr * k0_mul;
  const long bOff = zq * sBq + zr * sBr + (long)zr * k0_mul;
  const long cOff = zq * sCq + zr * sCr;

  __shared__ __align__(16) short As[128 * 64];
  __shared__ __align__(16) short Bs[128 * 64];

  const long m0 = (long)blockIdx.x * 128;
  const long n0 = (long)blockIdx.y * 128;

  const int wave = tid >> 6, lane = tid & 63;
  const int wm = (wave >> 1) * 64, wn = (wave & 1) * 64;
  const int mlan = lane & 15, kg = lane >> 4;

  f32x4 acc[4][4] = {};

  const int g_src = ((lane & 7) ^ (lane >> 3)) * 8;  // swizzled src granule
  const int lrow = lane >> 3;
  short* lA = As + wave * 2048 + lane * 8;
  short* lB = Bs + wave * 2048 + lane * 8;

  const int gi0 = ((kg ^ (mlan & 7)) * 8);
  const int gi1 = gi0 ^ 32;

  const int nk = klen >> 6;
#pragma unroll 1
  for (int t = 0; t < TERMS; ++t) {
    const short* Abase = ((TERMS == 3 && t == 2) ? A2g : Ag) + aOff;
    const short* Bbase = ((TERMS == 3 && t == 1) ? B2g : Bg) + bOff;
    const short* ga = Abase + (m0 + wave * 32 + lrow) * (long)lda + g_src;
    const short* gb = Bbase + (n0 + wave * 32 + lrow) * (long)ldb + g_src;
#pragma unroll 1
    for (int kt = 0; kt < nk; ++kt) {
      const int kb = kt * 64;
      __syncthreads();
      load16(ga + kb, lA);
      load16(ga + 8 * (long)lda + kb, lA + 512);
      load16(ga + 16 * (long)lda + kb, lA + 1024);
      load16(ga + 24 * (long)lda + kb, lA + 1536);
      load16(gb + kb, lB);
      load16(gb + 8 * (long)ldb + kb, lB + 512);
      load16(gb + 16 * (long)ldb + kb, lB + 1024);
      load16(gb + 24 * (long)ldb + kb, lB + 1536);
      __syncthreads();
      s16x8 af[2][4], bq[2][4];
      const short* pA = As + (wm + mlan) * 64;
      const short* pB = Bs + (wn + mlan) * 64;
#pragma unroll
      for (int i = 0; i < 4; ++i) {
        af[0][i] = *(const s16x8*)(pA + i * 1024 + gi0);
        af[1][i] = *(const s16x8*)(pA + i * 1024 + gi1);
        bq[0][i] = *(const s16x8*)(pB + i * 1024 + gi0);
        bq[1][i] = *(const s16x8*)(pB + i * 1024 + gi1);
      }
#pragma unroll
      for (int h = 0; h < 2; ++h)
#pragma unroll
        for (int mi = 0; mi < 4; ++mi)
#pragma unroll
          for (int ni = 0; ni < 4; ++ni)
            acc[mi][ni] = __builtin_amdgcn_mfma_f32_16x16x32_bf16(
                af[h][mi], bq[h][ni], acc[mi][ni], 0, 0, 0);
    }
  }

  const int rq = (lane >> 4) * 4;
  if (EPI == 5) {
#pragma unroll
    for (int mi = 0; mi < 4; ++mi) {
#pragma unroll
      for (int r = 0; r < 4; ++r) {
        long row = m0 + wm + mi * 16 + rq + r;
        float s = 0.f;
#pragma unroll
        for (int ni = 0; ni < 4; ++ni) {
          long col = n0 + wn + ni * 16 + mlan;
          float v = __expf(acc[mi][ni][r]);
          ((short*)Cg)[cOff + row * (long)ldc + col] = f2bf(v);
          s += v;
        }
        s += __shfl_xor(s, 1);
        s += __shfl_xor(s, 2);
        s += __shfl_xor(s, 4);
        s += __shfl_xor(s, 8);
        if (mlan == 0) atomicAdd((float*)C2g + row, s);
      }
    }
    return;
  }
#pragma unroll
  for (int mi = 0; mi < 4; ++mi) {
#pragma unroll
    for (int ni = 0; ni < 4; ++ni) {
#pragma unroll
      for (int r = 0; r < 4; ++r) {
        long row = m0 + wm + mi * 16 + rq + r;
        long col = n0 + wn + ni * 16 + mlan;
        float v = acc[mi][ni][r];
        long o = cOff + row * (long)ldc + col;
        if (EPI == 1) {
          atomicAdd((float*)Cg + o, v);
        } else if (EPI == 3) {
          ((float*)Cg)[o] = v;
        } else if (EPI == 4) {
          short h = f2bf(v);
          ((short*)Cg)[o] = h;
          C2g[o] = f2bf(v - bf2f(h));
        } else {
          if (EPI == 2) v *= 1.0f / (1.0f + (float)row);
          ((short*)Cg)[o] = f2bf(v);
        }
      }
    }
  }
}

// ---------------------------------------------------------------------------
__global__ void __launch_bounds__(256) ln_rows(
    const float* __restrict__ src, const int* __restrict__ tok,
    const float* __restrict__ wte, const float* __restrict__ g,
    float* __restrict__ o32, short* __restrict__ ohi, short* __restrict__ olo,
    int mode) {
  int r = blockIdx.x, tid = threadIdx.x;
  const float* in;
  if (mode == 0)
    in = wte + (long)tok[r] * 512;
  else
    in = src + (long)r * 512;
  int d = tid * 2;
  float2 v = *(const float2*)(in + d);
  float s1 = v.x + v.y;
  float s2 = v.x * v.x + v.y * v.y;
  __shared__ float red[20];
  for (int o = 32; o > 0; o >>= 1) {
    s1 += __shfl_down(s1, o);
    s2 += __shfl_down(s2, o);
  }
  int wave = tid >> 6, lane = tid & 63;
  if (lane == 0) { red[wave] = s1; red[wave + 8] = s2; }
  __syncthreads();
  if (tid == 0) {
    float a = red[0] + red[1] + red[2] + red[3];
    float b = red[8] + red[9] + red[10] + red[11];
    float mean = a * (1.f / 512.f);
    float var = b * (1.f / 512.f) - mean * mean;
    red[16] = mean;
    red[17] = 1.0f / sqrtf(var + 1e-5f);
  }
  __syncthreads();
  float mean = red[16], rs = red[17];
  float2 gg = *(const float2*)(g + d);
  float y0 = (v.x - mean) * rs * gg.x;
  float y1 = (v.y - mean) * rs * gg.y;
  long o = (long)r * 512 + d;
  if (o32) { o32[o] = y0; o32[o + 1] = y1; }
  if (ohi) {
    short h0 = f2bf(y0), h1 = f2bf(y1);
    ohi[o] = h0; ohi[o + 1] = h1;
    if (olo) {
      olo[o] = f2bf(y0 - bf2f(h0));
      olo[o + 1] = f2bf(y1 - bf2f(h1));
    }
  }
}

// Attention softmax: raw (H,S,S) fp32 -> scale, clip(+-10), causal, softmax.
__global__ void __launch_bounds__(256) softmax_krn_k(
    const float* __restrict__ raw, float* __restrict__ k32,
    short* __restrict__ k16) {
  int bx = blockIdx.x;
  int h = bx >> 9, s = bx & 511;
  long base = ((long)h * 512 + s) * 512;
  int tid = threadIdx.x;
  const float scale = 0.04419417382415922f;  // 1/sqrt(512)
  float e0 = 0.f, e1 = 0.f, l = 0.f;
  int t0 = tid, t1 = tid + 256;
  if (t0 <= s) {
    float v = raw[base + t0] * scale;
    v = fminf(fmaxf(v, -10.f), 10.f);
    e0 = __expf(v); l += e0;
  }
  if (t1 <= s) {
    float v = raw[base + t1] * scale;
    v = fminf(fmaxf(v, -10.f), 10.f);
    e1 = __expf(v); l += e1;
  }
  for (int o = 32; o > 0; o >>= 1) l += __shfl_down(l, o);
  __shared__ float red[10];
  int wave = tid >> 6, lane = tid & 63;
  if (lane == 0) red[wave] = l;
  __syncthreads();
  if (tid == 0) red[8] = 1.0f / (red[0] + red[1] + red[2] + red[3]);
  __syncthreads();
  float inv = red[8];
  k32[base + t0] = e0 * inv;
  k16[base + t0] = f2bf(e0 * inv);
  k32[base + t1] = e1 * inv;
  k16[base + t1] = f2bf(e1 * inv);
}

// Transpose+cast: in (RxC) f32 -> out (CxR) bf16 hi (and optional lo).
__global__ void __launch_bounds__(256) transpose_cast(
    const float* __restrict__ in, short* __restrict__ hi,
    short* __restrict__ lo, int R, int C) {
  long bo = (long)blockIdx.z * R * C;
  const float* inp = in + bo;
  short* ho = hi + bo;
  short* lop = lo ? lo + bo : nullptr;
  int c0 = blockIdx.x * 64, r0 = blockIdx.y * 64;
  __shared__ float tl[64][65];
  int tid = threadIdx.x;
  for (int it = 0; it < 16; ++it) {
    int idx = it * 256 + tid;
    int rr = idx >> 6, cc = idx & 63;
    tl[rr][cc] = inp[(long)(r0 + rr) * C + (c0 + cc)];
  }
  __syncthreads();
  for (int it = 0; it < 16; ++it) {
    int idx = it * 256 + tid;
    int rr = idx >> 6, cc = idx & 63;
    float v = tl[cc][rr];
    long o = (long)(c0 + rr) * R + (r0 + cc);
    short hh = f2bf(v);
    ho[o] = hh;
    if (lop) lop[o] = f2bf(v - bf2f(hh));
  }
}

// f32 transpose: in (RxC) -> out (CxR). grid (C/64, R/64).
__global__ void __launch_bounds__(256) transpose_f32(
    const float* __restrict__ in, float* __restrict__ outp, int R, int C) {
  int c0 = blockIdx.x * 64, r0 = blockIdx.y * 64;
  __shared__ float tlf[64][65];
  int tid = threadIdx.x;
  for (int it = 0; it < 16; ++it) {
    int idx = it * 256 + tid;
    int rr = idx >> 6, cc = idx & 63;
    tlf[rr][cc] = in[(long)(r0 + rr) * C + (c0 + cc)];
  }
  __syncthreads();
  for (int it = 0; it < 16; ++it) {
    int idx = it * 256 + tid;
    int rr = idx >> 6, cc = idx & 63;
    outp[(long)(c0 + rr) * R + (r0 + cc)] = tlf[cc][rr];
  }
}

// Elementwise f32 -> bf16 hi (and optional lo residual). n4 = n/4.
__global__ void __launch_bounds__(256) cast_hilo(
    const float* __restrict__ in, short* __restrict__ hi,
    short* __restrict__ lo, long n4) {
  long i = (long)blockIdx.x * 256 + threadIdx.x;
  if (i >= n4) return;
  float4 v = ((const float4*)in)[i];
  s16x4 h;
  h[0] = f2bf(v.x); h[1] = f2bf(v.y); h[2] = f2bf(v.z); h[3] = f2bf(v.w);
  *(s16x4*)(hi + i * 4) = h;
  if (lo) {
    s16x4 L;
    L[0] = f2bf(v.x - bf2f(h[0])); L[1] = f2bf(v.y - bf2f(h[1]));
    L[2] = f2bf(v.z - bf2f(h[2])); L[3] = f2bf(v.w - bf2f(h[3]));
    *(s16x4*)(lo + i * 4) = L;
  }
}

// Column mean of wte (32000x512) -> cm[512].
__global__ void __launch_bounds__(256) colmean_k(const float* __restrict__ wte,
                                                 float* __restrict__ cm) {
  int d = threadIdx.x * 2;
  long r0 = (long)blockIdx.x * 256;
  float a0 = 0.f, a1 = 0.f;
  for (int r = 0; r < 256; r++) {
    float2 v = *(const float2*)(wte + (r0 + r) * 512 + d);
    a0 += v.x; a1 += v.y;
  }
  atomicAdd(&cm[d], a0 * (1.f / 32000.f));
  atomicAdd(&cm[d + 1], a1 * (1.f / 32000.f));
}

// Vm tile kernel: v = e - (sum of 10 bf16 partials)/L (or e - colmean at l=0).
// Writes vmT16 (b,e,t) if store; fuses the fp32 shadow dot
// dl[b,h,e] += sum_t krn32[h,511,t] * v / 512 (per-tile, LDS-reduced).
__global__ void __launch_bounds__(256) vm_k(
    const float* __restrict__ e32, const short* __restrict__ part,
    const float* __restrict__ cm, const float* __restrict__ Lrow,
    const float* __restrict__ krn32, int useCm, int store,
    short* __restrict__ vmT, float* __restrict__ dl) {
  int b = blockIdx.z, t0 = blockIdx.y * 64, e0 = blockIdx.x * 64;
  __shared__ short tl[64][72];
  __shared__ float kl[4][64];
  __shared__ float dred[4][4][64];  // [wave][h][e]
  int tid = threadIdx.x;
  int w = tid >> 6, cx = tid & 63;
  kl[w][cx] = krn32[((long)w * 512 + 511) * 512 + t0 + cx];
  __syncthreads();
  long base = ((long)b * 512 + t0) * 512 + e0;
  float accH[4] = {0.f, 0.f, 0.f, 0.f};
  for (int it = 0; it < 16; ++it) {
    int idx = it * 256 + tid;
    int rr = idx >> 6, cc = idx & 63;
    long o = base + (long)rr * 512 + cc;
    float v;
    if (useCm) {
      v = e32[o] - cm[e0 + cc];
    } else {
      float s = 0.f;
#pragma unroll
      for (int p = 0; p < 10; ++p) s += bf2f(part[(long)p * 1048576 + o]);
      v = e32[o] - s / Lrow[b * 512 + t0 + rr];
    }
    if (store) tl[rr][cc] = f2bf(v);
#pragma unroll
    for (int h = 0; h < 4; ++h) accH[h] += v * kl[h][rr];
  }
#pragma unroll
  for (int h = 0; h < 4; ++h) dred[w][h][cx] = accH[h];
  __syncthreads();
  if (store) {
    for (int it = 0; it < 16; ++it) {
      int idx = it * 256 + tid;
      int rr = idx >> 6, cc = idx & 63;
      vmT[((long)b * 512 + (e0 + rr)) * 512 + (t0 + cc)] = tl[cc][rr];
    }
  }
  float s = dred[0][w][cx] + dred[1][w][cx] + dred[2][w][cx] + dred[3][w][cx];
  atomicAdd(&dl[(long)b * 2048 + w * 512 + e0 + cx], s * (1.f / 512.f));
}

// f_last[b, d0+lane] += sum_k dl[b,k] * WoT[k, d] (fp32, coalesced).
__global__ void __launch_bounds__(256) flast_k(
    const float* __restrict__ dl, const float* __restrict__ WoT,
    float* __restrict__ fl) {
  int b = blockIdx.y, d0 = blockIdx.x * 64;
  int tid = threadIdx.x, w = tid >> 6, lane = tid & 63;
  __shared__ float ds[2048];
  __shared__ float red[4][64];
  for (int i = tid; i < 2048; i += 256) ds[i] = dl[(long)b * 2048 + i];
  __syncthreads();
  float acc = 0.f;
  const float* wp = WoT + (long)(w * 512) * 512 + d0 + lane;
  for (int k = 0; k < 512; ++k) acc += ds[w * 512 + k] * wp[(long)k * 512];
  red[w][lane] = acc;
  __syncthreads();
  if (w == 0) {
    float s = red[0][lane] + red[1][lane] + red[2][lane] + red[3][lane];
    fl[(long)b * 512 + d0 + lane] += s;
  }
}

// fk32 += sum of 4 bf16 partial slabs; fk16 = bf16(fk32). grid 1024x256.
__global__ void __launch_bounds__(256) fkupdate_k(
    const short* __restrict__ part, float* __restrict__ fk32,
    short* __restrict__ fk16) {
  long i = (long)blockIdx.x * 256 + threadIdx.x;  // over 262144 float4s
  float4 s = ((const float4*)fk32)[i];
#pragma unroll
  for (int p = 0; p < 4; ++p) {
    s16x4 h = *(const s16x4*)(part + (long)p * 1048576 + i * 4);
    s.x += bf2f(h[0]); s.y += bf2f(h[1]);
    s.z += bf2f(h[2]); s.w += bf2f(h[3]);
  }
  ((float4*)fk32)[i] = s;
  s16x4 o;
  o[0] = f2bf(s.x); o[1] = f2bf(s.y); o[2] = f2bf(s.z); o[3] = f2bf(s.w);
  *(s16x4*)(fk16 + i * 4) = o;
}

// logits[b,v] = dot(outln[b,:], wte[v,:]) fp32.
__global__ void __launch_bounds__(256) logits_k(
    const float* __restrict__ outln, const float* __restrict__ wte,
    float* __restrict__ out) {
  int tid = threadIdx.x, wave = tid >> 6, lane = tid & 63;
  float o[4][8];
#pragma unroll
  for (int b = 0; b < 4; b++) {
    float4 q0 = *(const float4*)(outln + b * 512 + lane * 8);
    float4 q1 = *(const float4*)(outln + b * 512 + lane * 8 + 4);
    o[b][0] = q0.x; o[b][1] = q0.y; o[b][2] = q0.z; o[b][3] = q0.w;
    o[b][4] = q1.x; o[b][5] = q1.y; o[b][6] = q1.z; o[b][7] = q1.w;
  }
  int vbase = blockIdx.x * 64 + wave * 16;
  for (int i = 0; i < 16; i++) {
    int v = vbase + i;
    const float* row = wte + (long)v * 512 + lane * 8;
    float4 x0 = *(const float4*)row;
    float4 x1 = *(const float4*)(row + 4);
    float xr[8] = {x0.x, x0.y, x0.z, x0.w, x1.x, x1.y, x1.z, x1.w};
    float d0 = 0, d1 = 0, d2 = 0, d3 = 0;
#pragma unroll
    for (int j = 0; j < 8; j++) {
      d0 += o[0][j] * xr[j]; d1 += o[1][j] * xr[j];
      d2 += o[2][j] * xr[j]; d3 += o[3][j] * xr[j];
    }
    for (int off = 32; off > 0; off >>= 1) {
      d0 += __shfl_down(d0, off); d1 += __shfl_down(d1, off);
      d2 += __shfl_down(d2, off); d3 += __shfl_down(d3, off);
    }
    if (lane == 0) {
      out[v] = d0; out[32000 + v] = d1; out[64000 + v] = d2;
      out[96000 + v] = d3;
    }
  }
}

// ---------------------------------------------------------------------------
extern "C" void kernel_launch(void* const* d_in, const int* in_sizes, int n_in,
                              void* d_out, int out_size, void* d_ws,
                              size_t ws_size, hipStream_t stream) {
  (void)in_sizes; (void)n_in; (void)out_size;
  const int* x = (const int*)d_in[0];
  const float* wte = (const float*)d_in[1];
  const float* wpe = (const float*)d_in[2];
  const float* g_e = (const float*)d_in[3];
  const float* g_p = (const float*)d_in[4];
  const float* g_f = (const float*)d_in[5];
  const float* W_q = (const float*)d_in[6];
  const float* W_k = (const float*)d_in[7];
  const float* W_o = (const float*)d_in[8];
  float* out = (float*)d_out;

  char* ws = (char*)d_ws;
  size_t off = 0;
  auto alloc = [&](size_t b) {
    size_t o = off;
    off += (b + 255) & ~(size_t)255;
    return o;
  };
  const long HS = 262144;  // 512*512
  short* wte16 = (short*)(ws + alloc(32000L * 512 * 2));
  short* wteT16 = (short*)(ws + alloc(32000L * 512 * 2));
  // Scratch union (21 MB): setup {wqkt_hi/lo, qk_hi/lo, sATT} then per-layer
  // {exw partial slabs (10x bf16)} then {fk partial slabs (4x bf16)}.
  char* u = ws + alloc(10L * 1048576 * 2);
  short* wqkt_hi = (short*)u;                         // 4 MB (Q then K)
  short* wqkt_lo = (short*)(u + 4194304);             // 4 MB
  short* qk_hi = (short*)(u + 8388608);               // 4 MB
  short* qk_lo = (short*)(u + 12582912);              // 4 MB
  float* sATT = (float*)(u + 16777216);               // 4 MB
  short* exw_part = (short*)u;                        // 10 x 2 MB
  short* fkpart = (short*)u;                          // 4 x 2 MB
  short* wo16 = (short*)(ws + alloc(512L * 2048 * 2));
  float* WoT = (float*)(ws + alloc(2048L * 512 * 4));
  short* p_hi = (short*)(ws + alloc(513L * 512 * 2));
  short* p_lo = (short*)(ws + alloc(513L * 512 * 2));
  float* e32 = (float*)(ws + alloc(2048L * 512 * 4));
  float* colmean = (float*)(ws + alloc(512 * 4));
  float* krn32 = (float*)(ws + alloc(4L * HS * 4));
  short* krn16 = (short*)(ws + alloc(4L * HS * 2));
  short* S16 = (short*)(ws + alloc(2048L * 32000 * 2));
  float* Lrow = (float*)(ws + alloc(2048L * 4));
  short* vmT16 = (short*)(ws + alloc(2048L * 512 * 2));
  short* delta16 = (short*)(ws + alloc(2048L * 2048 * 2));
  float* fk32 = (float*)(ws + alloc(2048L * 512 * 4));
  short* fk16 = (short*)(ws + alloc(2048L * 512 * 2));
  float* flast = (float*)(ws + alloc(4L * 512 * 4));
  float* dl = (float*)(ws + alloc(4L * 2048 * 4));
  float* outln = (float*)(ws + alloc(4L * 512 * 4));
  if (off > ws_size) return;  // ws too small: bail (out stays zero)

  hipMemsetAsync(colmean, 0, 512 * 4, stream);
  hipMemsetAsync(fk32, 0, 2048L * 512 * 4, stream);
  hipMemsetAsync(flast, 0, 4L * 512 * 4, stream);

  // --- setup casts / transposes ---
  cast_hilo<<<16000, 256, 0, stream>>>(wte, wte16, nullptr, 32000L * 512 / 4);
  colmean_k<<<125, 256, 0, stream>>>(wte, colmean);
  transpose_cast<<<dim3(8, 500, 1), 256, 0, stream>>>(wte, wteT16, nullptr,
                                                      32000, 512);
  transpose_cast<<<dim3(8, 8, 4), 256, 0, stream>>>(W_q, wqkt_hi, wqkt_lo, 512,
                                                    512);
  transpose_cast<<<dim3(8, 8, 4), 256, 0, stream>>>(
      W_k, wqkt_hi + 4 * HS, wqkt_lo + 4 * HS, 512, 512);
  cast_hilo<<<1024, 256, 0, stream>>>(W_o, wo16, nullptr, 512L * 2048 / 4);
  transpose_f32<<<dim3(32, 8), 256, 0, stream>>>(W_o, WoT, 512, 2048);
  ln_rows<<<2048, 256, 0, stream>>>(nullptr, x, wte, g_e, e32, nullptr, nullptr,
                                    0);
  ln_rows<<<513, 256, 0, stream>>>(wpe, nullptr, nullptr, g_p, nullptr, p_hi,
                                   p_lo, 1);

  // --- Q|K then QK^T, fused 3-term split-bf16 launches ---
  gemm_nt<4, 3><<<dim3(4, 4, 8), 256, 0, stream>>>(
      p_hi + 512, wqkt_hi, p_lo + 512, wqkt_lo, qk_hi, qk_lo, 512, 512, 512,
      512, 0, 4, /*sAq*/ -512, /*sAr*/ 0, /*sBq*/ 4 * HS, /*sBr*/ HS,
      /*sCq*/ 4 * HS, /*sCr*/ HS);
  gemm_nt<3, 3><<<dim3(4, 4, 4), 256, 0, stream>>>(
      qk_hi, qk_hi + 4 * HS, qk_lo, qk_lo + 4 * HS, sATT, nullptr, 512, 512,
      512, 512, 0, 4, 0, HS, 0, HS, 0, HS);
  softmax_krn_k<<<2048, 256, 0, stream>>>(sATT, krn32, krn16);

  // --- layer loop ---
  for (int l = 0; l < 4; ++l) {
    if (l > 0) {
      hipMemsetAsync(Lrow, 0, 2048L * 4, stream);
      // S16 = exp(f_k @ wte^T), Lrow = row sums  (M=2048, N=32000, K=512)
      gemm_nt<5, 1><<<dim3(16, 250, 1), 256, 0, stream>>>(
          fk16, wte16, nullptr, nullptr, S16, (short*)Lrow, 512, 512, 32000,
          512, 0, 1, 0, 0, 0, 0, 0, 0);
      // exw partials = expS @ wte, split-K=10, bf16 slabs, no atomics
      gemm_nt<0, 1><<<dim3(16, 4, 10), 256, 0, stream>>>(
          S16, wteT16, nullptr, nullptr, exw_part, nullptr, 32000, 32000, 512,
          3200, 3200, 10, 0, 0, 0, 0, 0, 1048576L);
    }
    hipMemsetAsync(dl, 0, 4L * 2048 * 4, stream);
    vm_k<<<dim3(8, 8, 4), 256, 0, stream>>>(e32, exw_part, colmean, Lrow,
                                            krn32, (l == 0) ? 1 : 0,
                                            (l < 3) ? 1 : 0, vmT16, dl);
    flast_k<<<dim3(8, 4), 256, 0, stream>>>(dl, WoT, flast);
    if (l < 3) {
      // delta[b,h] = krn[h] @ Vm[b], scaled 1/(1+s), packed (b,s,h*512+e)
      gemm_nt<2, 1><<<dim3(4, 4, 16), 256, 0, stream>>>(
          krn16, vmT16, nullptr, nullptr, delta16, nullptr, 512, 512, 2048,
          512, 0, 4, 0, HS, HS, 0, 1048576L, 512);
      // fk partials = delta @ W_o^T, split-K=4, bf16 slabs
      gemm_nt<0, 1><<<dim3(16, 4, 4), 256, 0, stream>>>(
          delta16, wo16, nullptr, nullptr, fkpart, nullptr, 2048, 2048, 512,
          512, 512, 4, 0, 0, 0, 0, 0, 1048576L);
      fkupdate_k<<<1024, 256, 0, stream>>>(fkpart, fk32, fk16);
    }
  }

  // --- final LN + logits (pure fp32) ---
  ln_rows<<<4, 256, 0, stream>>>(flast, nullptr, nullptr, g_f, outln, nullptr,
                                 nullptr, 2);
  logits_k<<<500, 256, 0, stream>>>(outln, wte, out);
}

// Round 6
// 996.672 us; speedup vs baseline: 1.7925x; 1.0546x over previous
//
#include <hip/hip_runtime.h>
#include <stdint.h>

// ---------------------------------------------------------------------------
// Shapes: V=32000, D=512, H=4, L=4, B=4, S=512. Output logits (4,1,32000) f32.
//  - bf16 MFMA vocab GEMMs (softmax damps bf16 noise).
//  - split-bf16 3-term MFMA for Q/K/QK^T (near-fp32 krn).
//  - fp32 shadow path for f_k[:,511,:] (only row reaching output).
//  - layer 0: softmax(0) uniform -> ex_wte = colmean(wte) exactly.
//  - R2: BK=64, XOR-swizzled LDS, 16B DMA staging.
//  - R4: vocab softmax fused into scores epilogue (exp + row-sum atomics).
//  - R5: no atomics in big GEMMs (bf16 partial slabs); dlast fused into vm_k.
//  - R6: P matrix in fp8 e4m3 (6% noise damped to ~7e-6 by the 32000-sum);
//    ex_wte is an fp8xfp8 MFMA GEMM (BK=128, same byte geometry); prep_wte
//    fuses wte cast + transpose-fp8(x64) + colmean into one pass.
// ---------------------------------------------------------------------------

typedef __attribute__((ext_vector_type(8))) short s16x8;
typedef __attribute__((ext_vector_type(4))) short s16x4;
typedef __attribute__((ext_vector_type(4))) float f32x4;

__device__ __forceinline__ short f2bf(float f) {
  unsigned u = __float_as_uint(f);
  unsigned r = (u + 0x7FFFu + ((u >> 16) & 1u)) >> 16;  // RNE
  return (short)r;
}
__device__ __forceinline__ float bf2f(short u) {
  unsigned v = ((unsigned)(unsigned short)u) << 16;
  return __uint_as_float(v);
}
// fp8 e4m3fn converters. fast: assumes x in [2^-6, 448) (positive, normal).
__device__ __forceinline__ unsigned char f2fp8_fast(float x) {
  unsigned u = __float_as_uint(x);
  u += 0x7FFFFu + ((u >> 20) & 1u);  // RNE into 3-bit mantissa
  return (unsigned char)(((((u >> 23) & 0xff) - 120) << 3) | ((u >> 20) & 7));
}
__device__ __forceinline__ unsigned char f2fp8_full(float x) {
  unsigned u = __float_as_uint(x);
  unsigned sg = (u >> 24) & 0x80;
  u &= 0x7fffffff;
  float a = __uint_as_float(u);
  if (a >= 448.f) return (unsigned char)(sg | 0x7e);
  if (a < 0.015625f) {  // subnormal: step 2^-9
    int m = (int)rintf(a * 512.f);
    return (unsigned char)(sg | m);
  }
  u += 0x7FFFFu + ((u >> 20) & 1u);
  int eb = (int)((u >> 23) & 0xff) - 120;
  if (eb >= 16) return (unsigned char)(sg | 0x7e);
  return (unsigned char)(sg | (eb << 3) | ((u >> 20) & 7));
}

__device__ __forceinline__ void load16(const void* g, void* l) {
  __builtin_amdgcn_global_load_lds(
      (__attribute__((address_space(1))) void*)g,
      (__attribute__((address_space(3))) void*)l, 16, 0, 0);
}

// ---------------------------------------------------------------------------
// bf16 NT GEMM: C[m,n] (+)= sum_k A[m,k]*B[n,k]. 128x128 tile, BK=64, 4 waves.
// XOR-swizzled LDS; global_load_lds staging. z: zq=z/zdiv, zr=z%zdiv;
// k0 = zr*k0_mul applied to A and B. TERMS=3: hi*hi + hi*lo + lo*hi.
// EPI: 0 bf16 store; 2 bf16 * 1/(1+row); 3 f32 store; 4 bf16 hi->Cg lo->C2g;
//      5 fp8 exp(v)->Cg + row-sum atomics->(float*)C2g.
// ---------------------------------------------------------------------------
template <int EPI, int TERMS>
__global__ void __launch_bounds__(256) gemm_nt(
    const short* __restrict__ Ag, const short* __restrict__ Bg,
    const short* __restrict__ A2g, const short* __restrict__ B2g,
    void* __restrict__ Cg, short* __restrict__ C2g, int lda, int ldb, int ldc,
    int klen, int k0_mul, int zdiv, long sAq, long sAr, long sBq, long sBr,
    long sCq, long sCr) {
  const int tid = threadIdx.x;
  const int z = blockIdx.z;
  const int zq = z / zdiv, zr = z % zdiv;
  const long aOff = zq * sAq + zr * sAr + (long)zr * k0_mul;
  const long bOff = zq * sBq + zr * sBr + (long)zr * k0_mul;
  const long cOff = zq * sCq + zr * sCr;

  __shared__ __align__(16) short As[128 * 64];
  __shared__ __align__(16) short Bs[128 * 64];

  const long m0 = (long)blockIdx.x * 128;
  const long n0 = (long)blockIdx.y * 128;

  const int wave = tid >> 6, lane = tid & 63;
  const int wm = (wave >> 1) * 64, wn = (wave & 1) * 64;
  const int mlan = lane & 15, kg = lane >> 4;

  f32x4 acc[4][4] = {};

  const int g_src = ((lane & 7) ^ (lane >> 3)) * 8;  // swizzled src granule
  const int lrow = lane >> 3;
  short* lA = As + wave * 2048 + lane * 8;
  short* lB = Bs + wave * 2048 + lane * 8;

  const int gi0 = ((kg ^ (mlan & 7)) * 8);
  const int gi1 = gi0 ^ 32;

  const int nk = klen >> 6;
#pragma unroll 1
  for (int t = 0; t < TERMS; ++t) {
    const short* Abase = ((TERMS == 3 && t == 2) ? A2g : Ag) + aOff;
    const short* Bbase = ((TERMS == 3 && t == 1) ? B2g : Bg) + bOff;
    const short* ga = Abase + (m0 + wave * 32 + lrow) * (long)lda + g_src;
    const short* gb = Bbase + (n0 + wave * 32 + lrow) * (long)ldb + g_src;
#pragma unroll 1
    for (int kt = 0; kt < nk; ++kt) {
      const int kb = kt * 64;
      __syncthreads();
      load16(ga + kb, lA);
      load16(ga + 8 * (long)lda + kb, lA + 512);
      load16(ga + 16 * (long)lda + kb, lA + 1024);
      load16(ga + 24 * (long)lda + kb, lA + 1536);
      load16(gb + kb, lB);
      load16(gb + 8 * (long)ldb + kb, lB + 512);
      load16(gb + 16 * (long)ldb + kb, lB + 1024);
      load16(gb + 24 * (long)ldb + kb, lB + 1536);
      __syncthreads();
      s16x8 af[2][4], bq[2][4];
      const short* pA = As + (wm + mlan) * 64;
      const short* pB = Bs + (wn + mlan) * 64;
#pragma unroll
      for (int i = 0; i < 4; ++i) {
        af[0][i] = *(const s16x8*)(pA + i * 1024 + gi0);
        af[1][i] = *(const s16x8*)(pA + i * 1024 + gi1);
        bq[0][i] = *(const s16x8*)(pB + i * 1024 + gi0);
        bq[1][i] = *(const s16x8*)(pB + i * 1024 + gi1);
      }
#pragma unroll
      for (int h = 0; h < 2; ++h)
#pragma unroll
        for (int mi = 0; mi < 4; ++mi)
#pragma unroll
          for (int ni = 0; ni < 4; ++ni)
            acc[mi][ni] = __builtin_amdgcn_mfma_f32_16x16x32_bf16(
                af[h][mi], bq[h][ni], acc[mi][ni], 0, 0, 0);
    }
  }

  const int rq = (lane >> 4) * 4;
  if (EPI == 5) {
#pragma unroll
    for (int mi = 0; mi < 4; ++mi) {
#pragma unroll
      for (int r = 0; r < 4; ++r) {
        long row = m0 + wm + mi * 16 + rq + r;
        float s = 0.f;
#pragma unroll
        for (int ni = 0; ni < 4; ++ni) {
          long col = n0 + wn + ni * 16 + mlan;
          float v = __expf(acc[mi][ni][r]);
          ((unsigned char*)Cg)[cOff + row * (long)ldc + col] = f2fp8_fast(v);
          s += v;
        }
        s += __shfl_xor(s, 1);
        s += __shfl_xor(s, 2);
        s += __shfl_xor(s, 4);
        s += __shfl_xor(s, 8);
        if (mlan == 0) atomicAdd((float*)C2g + row, s);
      }
    }
    return;
  }
#pragma unroll
  for (int mi = 0; mi < 4; ++mi) {
#pragma unroll
    for (int ni = 0; ni < 4; ++ni) {
#pragma unroll
      for (int r = 0; r < 4; ++r) {
        long row = m0 + wm + mi * 16 + rq + r;
        long col = n0 + wn + ni * 16 + mlan;
        float v = acc[mi][ni][r];
        long o = cOff + row * (long)ldc + col;
        if (EPI == 3) {
          ((float*)Cg)[o] = v;
        } else if (EPI == 4) {
          short h = f2bf(v);
          ((short*)Cg)[o] = h;
          C2g[o] = f2bf(v - bf2f(h));
        } else {
          if (EPI == 2) v *= 1.0f / (1.0f + (float)row);
          ((short*)Cg)[o] = f2bf(v);
        }
      }
    }
  }
}

// ---------------------------------------------------------------------------
// fp8 NT GEMM (ex_wte): C_part[z][m,n] = sum_k A[m,k]*B[n,k] over K-chunk z.
// 128x128 tile, BK=128 fp8 elems (=128 B, same byte geometry as bf16 BK=64).
// A = P fp8 (M x 32000), B = wteT8 (512 x 32000). bf16 partial slab out.
// ---------------------------------------------------------------------------
__global__ void __launch_bounds__(256) gemm8(
    const unsigned char* __restrict__ Ag, const unsigned char* __restrict__ Bg,
    short* __restrict__ Cg, int lda, int ldb, int ldc, int klen, int k0_mul,
    long sCr) {
  const int tid = threadIdx.x;
  const int zr = blockIdx.z;
  const long kOff = (long)zr * k0_mul;
  const long cOff = (long)zr * sCr;

  __shared__ __align__(16) unsigned char As[128 * 128];
  __shared__ __align__(16) unsigned char Bs[128 * 128];

  const long m0 = (long)blockIdx.x * 128;
  const long n0 = (long)blockIdx.y * 128;

  const int wave = tid >> 6, lane = tid & 63;
  const int wm = (wave >> 1) * 64, wn = (wave & 1) * 64;
  const int mlan = lane & 15, kg = lane >> 4;

  f32x4 acc[4][4] = {};

  const int g_src = ((lane & 7) ^ (lane >> 3)) * 16;  // byte offset
  const int lrow = lane >> 3;
  unsigned char* lA = As + wave * 4096 + lane * 16;
  unsigned char* lB = Bs + wave * 4096 + lane * 16;

  const unsigned char* ga =
      Ag + kOff + (m0 + wave * 32 + lrow) * (long)lda + g_src;
  const unsigned char* gb =
      Bg + kOff + (n0 + wave * 32 + lrow) * (long)ldb + g_src;

  const int nk = klen >> 7;
#pragma unroll 1
  for (int kt = 0; kt < nk; ++kt) {
    const int kb = kt * 128;
    __syncthreads();
    load16(ga + kb, lA);
    load16(ga + 8 * (long)lda + kb, lA + 1024);
    load16(ga + 16 * (long)lda + kb, lA + 2048);
    load16(ga + 24 * (long)lda + kb, lA + 3072);
    load16(gb + kb, lB);
    load16(gb + 8 * (long)ldb + kb, lB + 1024);
    load16(gb + 16 * (long)ldb + kb, lB + 2048);
    load16(gb + 24 * (long)ldb + kb, lB + 3072);
    __syncthreads();
    const unsigned char* pA = As + (wm + mlan) * 128;
    const unsigned char* pB = Bs + (wn + mlan) * 128;
#pragma unroll
    for (int h = 0; h < 4; ++h) {
      const int go = (((2 * h + (kg >> 1)) ^ (mlan & 7)) * 16) + (kg & 1) * 8;
      long af[4], bq[4];
#pragma unroll
      for (int i = 0; i < 4; ++i) {
        af[i] = *(const long*)(pA + i * 2048 + go);
        bq[i] = *(const long*)(pB + i * 2048 + go);
      }
#pragma unroll
      for (int mi = 0; mi < 4; ++mi)
#pragma unroll
        for (int ni = 0; ni < 4; ++ni)
          acc[mi][ni] = __builtin_amdgcn_mfma_f32_16x16x32_fp8_fp8(
              af[mi], bq[ni], acc[mi][ni], 0, 0, 0);
    }
  }

  const int rq = (lane >> 4) * 4;
#pragma unroll
  for (int mi = 0; mi < 4; ++mi)
#pragma unroll
    for (int ni = 0; ni < 4; ++ni)
#pragma unroll
      for (int r = 0; r < 4; ++r) {
        long row = m0 + wm + mi * 16 + rq + r;
        long col = n0 + wn + ni * 16 + mlan;
        Cg[cOff + row * (long)ldc + col] = f2bf(acc[mi][ni][r]);
      }
}

// ---------------------------------------------------------------------------
__global__ void __launch_bounds__(256) ln_rows(
    const float* __restrict__ src, const int* __restrict__ tok,
    const float* __restrict__ wte, const float* __restrict__ g,
    float* __restrict__ o32, short* __restrict__ ohi, short* __restrict__ olo,
    int mode) {
  int r = blockIdx.x, tid = threadIdx.x;
  const float* in;
  if (mode == 0)
    in = wte + (long)tok[r] * 512;
  else
    in = src + (long)r * 512;
  int d = tid * 2;
  float2 v = *(const float2*)(in + d);
  float s1 = v.x + v.y;
  float s2 = v.x * v.x + v.y * v.y;
  __shared__ float red[20];
  for (int o = 32; o > 0; o >>= 1) {
    s1 += __shfl_down(s1, o);
    s2 += __shfl_down(s2, o);
  }
  int wave = tid >> 6, lane = tid & 63;
  if (lane == 0) { red[wave] = s1; red[wave + 8] = s2; }
  __syncthreads();
  if (tid == 0) {
    float a = red[0] + red[1] + red[2] + red[3];
    float b = red[8] + red[9] + red[10] + red[11];
    float mean = a * (1.f / 512.f);
    float var = b * (1.f / 512.f) - mean * mean;
    red[16] = mean;
    red[17] = 1.0f / sqrtf(var + 1e-5f);
  }
  __syncthreads();
  float mean = red[16], rs = red[17];
  float2 gg = *(const float2*)(g + d);
  float y0 = (v.x - mean) * rs * gg.x;
  float y1 = (v.y - mean) * rs * gg.y;
  long o = (long)r * 512 + d;
  if (o32) { o32[o] = y0; o32[o + 1] = y1; }
  if (ohi) {
    short h0 = f2bf(y0), h1 = f2bf(y1);
    ohi[o] = h0; ohi[o + 1] = h1;
    if (olo) {
      olo[o] = f2bf(y0 - bf2f(h0));
      olo[o + 1] = f2bf(y1 - bf2f(h1));
    }
  }
}

// Attention softmax: raw (H,S,S) fp32 -> scale, clip(+-10), causal, softmax.
__global__ void __launch_bounds__(256) softmax_krn_k(
    const float* __restrict__ raw, float* __restrict__ k32,
    short* __restrict__ k16) {
  int bx = blockIdx.x;
  int h = bx >> 9, s = bx & 511;
  long base = ((long)h * 512 + s) * 512;
  int tid = threadIdx.x;
  const float scale = 0.04419417382415922f;  // 1/sqrt(512)
  float e0 = 0.f, e1 = 0.f, l = 0.f;
  int t0 = tid, t1 = tid + 256;
  if (t0 <= s) {
    float v = raw[base + t0] * scale;
    v = fminf(fmaxf(v, -10.f), 10.f);
    e0 = __expf(v); l += e0;
  }
  if (t1 <= s) {
    float v = raw[base + t1] * scale;
    v = fminf(fmaxf(v, -10.f), 10.f);
    e1 = __expf(v); l += e1;
  }
  for (int o = 32; o > 0; o >>= 1) l += __shfl_down(l, o);
  __shared__ float red[10];
  int wave = tid >> 6, lane = tid & 63;
  if (lane == 0) red[wave] = l;
  __syncthreads();
  if (tid == 0) red[8] = 1.0f / (red[0] + red[1] + red[2] + red[3]);
  __syncthreads();
  float inv = red[8];
  k32[base + t0] = e0 * inv;
  k16[base + t0] = f2bf(e0 * inv);
  k32[base + t1] = e1 * inv;
  k16[base + t1] = f2bf(e1 * inv);
}

// Transpose+cast: in (RxC) f32 -> out (CxR) bf16 hi (and optional lo).
__global__ void __launch_bounds__(256) transpose_cast(
    const float* __restrict__ in, short* __restrict__ hi,
    short* __restrict__ lo, int R, int C) {
  long bo = (long)blockIdx.z * R * C;
  const float* inp = in + bo;
  short* ho = hi + bo;
  short* lop = lo ? lo + bo : nullptr;
  int c0 = blockIdx.x * 64, r0 = blockIdx.y * 64;
  __shared__ float tl[64][65];
  int tid = threadIdx.x;
  for (int it = 0; it < 16; ++it) {
    int idx = it * 256 + tid;
    int rr = idx >> 6, cc = idx & 63;
    tl[rr][cc] = inp[(long)(r0 + rr) * C + (c0 + cc)];
  }
  __syncthreads();
  for (int it = 0; it < 16; ++it) {
    int idx = it * 256 + tid;
    int rr = idx >> 6, cc = idx & 63;
    float v = tl[cc][rr];
    long o = (long)(c0 + rr) * R + (r0 + cc);
    short hh = f2bf(v);
    ho[o] = hh;
    if (lop) lop[o] = f2bf(v - bf2f(hh));
  }
}

// f32 transpose: in (RxC) -> out (CxR). grid (C/64, R/64).
__global__ void __launch_bounds__(256) transpose_f32(
    const float* __restrict__ in, float* __restrict__ outp, int R, int C) {
  int c0 = blockIdx.x * 64, r0 = blockIdx.y * 64;
  __shared__ float tlf[64][65];
  int tid = threadIdx.x;
  for (int it = 0; it < 16; ++it) {
    int idx = it * 256 + tid;
    int rr = idx >> 6, cc = idx & 63;
    tlf[rr][cc] = in[(long)(r0 + rr) * C + (c0 + cc)];
  }
  __syncthreads();
  for (int it = 0; it < 16; ++it) {
    int idx = it * 256 + tid;
    int rr = idx >> 6, cc = idx & 63;
    outp[(long)(c0 + rr) * R + (r0 + cc)] = tlf[cc][rr];
  }
}

// Elementwise f32 -> bf16. n4 = n/4.
__global__ void __launch_bounds__(256) cast_hilo(
    const float* __restrict__ in, short* __restrict__ hi,
    short* __restrict__ lo, long n4) {
  long i = (long)blockIdx.x * 256 + threadIdx.x;
  if (i >= n4) return;
  float4 v = ((const float4*)in)[i];
  s16x4 h;
  h[0] = f2bf(v.x); h[1] = f2bf(v.y); h[2] = f2bf(v.z); h[3] = f2bf(v.w);
  *(s16x4*)(hi + i * 4) = h;
  if (lo) {
    s16x4 L;
    L[0] = f2bf(v.x - bf2f(h[0])); L[1] = f2bf(v.y - bf2f(h[1]));
    L[2] = f2bf(v.z - bf2f(h[2])); L[3] = f2bf(v.w - bf2f(h[3]));
    *(s16x4*)(lo + i * 4) = L;
  }
}

// One pass over wte: wte16 (bf16 row-major) + wteT8 (fp8 e4m3, x64, e-major)
// + column mean. grid (8, 500).
__global__ void __launch_bounds__(256) prep_wte(
    const float* __restrict__ wte, short* __restrict__ w16,
    unsigned char* __restrict__ wT8, float* __restrict__ cm) {
  int c0 = blockIdx.x * 64, r0 = blockIdx.y * 64;
  __shared__ float tl[64][65];
  __shared__ float cred[4][64];
  int tid = threadIdx.x, w = tid >> 6, cx = tid & 63;
  float csum = 0.f;
  for (int it = 0; it < 16; ++it) {
    int idx = it * 256 + tid;
    int rr = idx >> 6, cc = idx & 63;
    float v = wte[(long)(r0 + rr) * 512 + c0 + cc];
    tl[rr][cc] = v;
    csum += v;
    w16[(long)(r0 + rr) * 512 + c0 + cc] = f2bf(v);
  }
  cred[w][cx] = csum;
  __syncthreads();
  if (w == 0) {
    float s = cred[0][cx] + cred[1][cx] + cred[2][cx] + cred[3][cx];
    atomicAdd(&cm[c0 + cx], s * (1.f / 32000.f));
  }
  for (int it = 0; it < 16; ++it) {
    int idx = it * 256 + tid;
    int rr = idx >> 6, cc = idx & 63;
    wT8[(long)(c0 + rr) * 32000 + r0 + cc] = f2fp8_full(tl[cc][rr] * 64.f);
  }
}

// Vm tile kernel: v = e - (sum of 10 bf16 partials)/(64*L) (or e - colmean at
// l=0). Writes vmT16 (b,e,t) if store; fuses the fp32 shadow dot
// dl[b,h,e] += sum_t krn32[h,511,t] * v / 512 (per-tile, LDS-reduced).
__global__ void __launch_bounds__(256) vm_k(
    const float* __restrict__ e32, const short* __restrict__ part,
    const float* __restrict__ cm, const float* __restrict__ Lrow,
    const float* __restrict__ krn32, int useCm, int store,
    short* __restrict__ vmT, float* __restrict__ dl) {
  int b = blockIdx.z, t0 = blockIdx.y * 64, e0 = blockIdx.x * 64;
  __shared__ short tl[64][72];
  __shared__ float kl[4][64];
  __shared__ float linv[64];
  __shared__ float dred[4][4][64];  // [wave][h][e]
  int tid = threadIdx.x;
  int w = tid >> 6, cx = tid & 63;
  kl[w][cx] = krn32[((long)w * 512 + 511) * 512 + t0 + cx];
  if (tid < 64 && !useCm)
    linv[tid] = 1.0f / (64.0f * Lrow[b * 512 + t0 + tid]);
  __syncthreads();
  long base = ((long)b * 512 + t0) * 512 + e0;
  float accH[4] = {0.f, 0.f, 0.f, 0.f};
  for (int it = 0; it < 16; ++it) {
    int idx = it * 256 + tid;
    int rr = idx >> 6, cc = idx & 63;
    long o = base + (long)rr * 512 + cc;
    float v;
    if (useCm) {
      v = e32[o] - cm[e0 + cc];
    } else {
      float s = 0.f;
#pragma unroll
      for (int p = 0; p < 10; ++p) s += bf2f(part[(long)p * 1048576 + o]);
      v = e32[o] - s * linv[rr];
    }
    if (store) tl[rr][cc] = f2bf(v);
#pragma unroll
    for (int h = 0; h < 4; ++h) accH[h] += v * kl[h][rr];
  }
#pragma unroll
  for (int h = 0; h < 4; ++h) dred[w][h][cx] = accH[h];
  __syncthreads();
  if (store) {
    for (int it = 0; it < 16; ++it) {
      int idx = it * 256 + tid;
      int rr = idx >> 6, cc = idx & 63;
      vmT[((long)b * 512 + (e0 + rr)) * 512 + (t0 + cc)] = tl[cc][rr];
    }
  }
  float s = dred[0][w][cx] + dred[1][w][cx] + dred[2][w][cx] + dred[3][w][cx];
  atomicAdd(&dl[(long)b * 2048 + w * 512 + e0 + cx], s * (1.f / 512.f));
}

// f_last[b, d0+lane] += sum_k dl[b,k] * WoT[k, d] (fp32, coalesced).
__global__ void __launch_bounds__(256) flast_k(
    const float* __restrict__ dl, const float* __restrict__ WoT,
    float* __restrict__ fl) {
  int b = blockIdx.y, d0 = blockIdx.x * 64;
  int tid = threadIdx.x, w = tid >> 6, lane = tid & 63;
  __shared__ float ds[2048];
  __shared__ float red[4][64];
  for (int i = tid; i < 2048; i += 256) ds[i] = dl[(long)b * 2048 + i];
  __syncthreads();
  float acc = 0.f;
  const float* wp = WoT + (long)(w * 512) * 512 + d0 + lane;
  for (int k = 0; k < 512; ++k) acc += ds[w * 512 + k] * wp[(long)k * 512];
  red[w][lane] = acc;
  __syncthreads();
  if (w == 0) {
    float s = red[0][lane] + red[1][lane] + red[2][lane] + red[3][lane];
    fl[(long)b * 512 + d0 + lane] += s;
  }
}

// fk32 += sum of 4 bf16 partial slabs; fk16 = bf16(fk32). grid 1024x256.
__global__ void __launch_bounds__(256) fkupdate_k(
    const short* __restrict__ part, float* __restrict__ fk32,
    short* __restrict__ fk16) {
  long i = (long)blockIdx.x * 256 + threadIdx.x;  // over 262144 float4s
  float4 s = ((const float4*)fk32)[i];
#pragma unroll
  for (int p = 0; p < 4; ++p) {
    s16x4 h = *(const s16x4*)(part + (long)p * 1048576 + i * 4);
    s.x += bf2f(h[0]); s.y += bf2f(h[1]);
    s.z += bf2f(h[2]); s.w += bf2f(h[3]);
  }
  ((float4*)fk32)[i] = s;
  s16x4 o;
  o[0] = f2bf(s.x); o[1] = f2bf(s.y); o[2] = f2bf(s.z); o[3] = f2bf(s.w);
  *(s16x4*)(fk16 + i * 4) = o;
}

// logits[b,v] = dot(outln[b,:], wte[v,:]) fp32.
__global__ void __launch_bounds__(256) logits_k(
    const float* __restrict__ outln, const float* __restrict__ wte,
    float* __restrict__ out) {
  int tid = threadIdx.x, wave = tid >> 6, lane = tid & 63;
  float o[4][8];
#pragma unroll
  for (int b = 0; b < 4; b++) {
    float4 q0 = *(const float4*)(outln + b * 512 + lane * 8);
    float4 q1 = *(const float4*)(outln + b * 512 + lane * 8 + 4);
    o[b][0] = q0.x; o[b][1] = q0.y; o[b][2] = q0.z; o[b][3] = q0.w;
    o[b][4] = q1.x; o[b][5] = q1.y; o[b][6] = q1.z; o[b][7] = q1.w;
  }
  int vbase = blockIdx.x * 64 + wave * 16;
  for (int i = 0; i < 16; i++) {
    int v = vbase + i;
    const float* row = wte + (long)v * 512 + lane * 8;
    float4 x0 = *(const float4*)row;
    float4 x1 = *(const float4*)(row + 4);
    float xr[8] = {x0.x, x0.y, x0.z, x0.w, x1.x, x1.y, x1.z, x1.w};
    float d0 = 0, d1 = 0, d2 = 0, d3 = 0;
#pragma unroll
    for (int j = 0; j < 8; j++) {
      d0 += o[0][j] * xr[j]; d1 += o[1][j] * xr[j];
      d2 += o[2][j] * xr[j]; d3 += o[3][j] * xr[j];
    }
    for (int off = 32; off > 0; off >>= 1) {
      d0 += __shfl_down(d0, off); d1 += __shfl_down(d1, off);
      d2 += __shfl_down(d2, off); d3 += __shfl_down(d3, off);
    }
    if (lane == 0) {
      out[v] = d0; out[32000 + v] = d1; out[64000 + v] = d2;
      out[96000 + v] = d3;
    }
  }
}

// ---------------------------------------------------------------------------
extern "C" void kernel_launch(void* const* d_in, const int* in_sizes, int n_in,
                              void* d_out, int out_size, void* d_ws,
                              size_t ws_size, hipStream_t stream) {
  (void)in_sizes; (void)n_in; (void)out_size;
  const int* x = (const int*)d_in[0];
  const float* wte = (const float*)d_in[1];
  const float* wpe = (const float*)d_in[2];
  const float* g_e = (const float*)d_in[3];
  const float* g_p = (const float*)d_in[4];
  const float* g_f = (const float*)d_in[5];
  const float* W_q = (const float*)d_in[6];
  const float* W_k = (const float*)d_in[7];
  const float* W_o = (const float*)d_in[8];
  float* out = (float*)d_out;

  char* ws = (char*)d_ws;
  size_t off = 0;
  auto alloc = [&](size_t b) {
    size_t o = off;
    off += (b + 255) & ~(size_t)255;
    return o;
  };
  const long HS = 262144;  // 512*512
  short* wte16 = (short*)(ws + alloc(32000L * 512 * 2));
  unsigned char* wteT8 = (unsigned char*)(ws + alloc(512L * 32000));
  // Scratch union (21 MB): setup {wqkt_hi/lo, qk_hi/lo, sATT} then per-layer
  // {exw partial slabs (10x bf16)} / {fk partial slabs (4x bf16)}.
  char* u = ws + alloc(10L * 1048576 * 2);
  short* wqkt_hi = (short*)u;                         // 4 MB (Q then K)
  short* wqkt_lo = (short*)(u + 4194304);             // 4 MB
  short* qk_hi = (short*)(u + 8388608);               // 4 MB
  short* qk_lo = (short*)(u + 12582912);              // 4 MB
  float* sATT = (float*)(u + 16777216);               // 4 MB
  short* exw_part = (short*)u;                        // 10 x 2 MB
  short* fkpart = (short*)u;                          // 4 x 2 MB
  short* wo16 = (short*)(ws + alloc(512L * 2048 * 2));
  float* WoT = (float*)(ws + alloc(2048L * 512 * 4));
  short* p_hi = (short*)(ws + alloc(513L * 512 * 2));
  short* p_lo = (short*)(ws + alloc(513L * 512 * 2));
  float* e32 = (float*)(ws + alloc(2048L * 512 * 4));
  float* colmean = (float*)(ws + alloc(512 * 4));
  float* krn32 = (float*)(ws + alloc(4L * HS * 4));
  short* krn16 = (short*)(ws + alloc(4L * HS * 2));
  unsigned char* S8 = (unsigned char*)(ws + alloc(2048L * 32000));
  float* Lrow = (float*)(ws + alloc(2048L * 4));
  short* vmT16 = (short*)(ws + alloc(2048L * 512 * 2));
  short* delta16 = (short*)(ws + alloc(2048L * 2048 * 2));
  float* fk32 = (float*)(ws + alloc(2048L * 512 * 4));
  short* fk16 = (short*)(ws + alloc(2048L * 512 * 2));
  float* flast = (float*)(ws + alloc(4L * 512 * 4));
  float* dl = (float*)(ws + alloc(4L * 2048 * 4));
  float* outln = (float*)(ws + alloc(4L * 512 * 4));
  if (off > ws_size) return;  // ws too small: bail (out stays zero)

  hipMemsetAsync(colmean, 0, 512 * 4, stream);
  hipMemsetAsync(fk32, 0, 2048L * 512 * 4, stream);
  hipMemsetAsync(flast, 0, 4L * 512 * 4, stream);

  // --- setup ---
  prep_wte<<<dim3(8, 500), 256, 0, stream>>>(wte, wte16, wteT8, colmean);
  transpose_cast<<<dim3(8, 8, 4), 256, 0, stream>>>(W_q, wqkt_hi, wqkt_lo, 512,
                                                    512);
  transpose_cast<<<dim3(8, 8, 4), 256, 0, stream>>>(
      W_k, wqkt_hi + 4 * HS, wqkt_lo + 4 * HS, 512, 512);
  cast_hilo<<<1024, 256, 0, stream>>>(W_o, wo16, nullptr, 512L * 2048 / 4);
  transpose_f32<<<dim3(32, 8), 256, 0, stream>>>(W_o, WoT, 512, 2048);
  ln_rows<<<2048, 256, 0, stream>>>(nullptr, x, wte, g_e, e32, nullptr, nullptr,
                                    0);
  ln_rows<<<513, 256, 0, stream>>>(wpe, nullptr, nullptr, g_p, nullptr, p_hi,
                                   p_lo, 1);

  // --- Q|K then QK^T, fused 3-term split-bf16 launches ---
  gemm_nt<4, 3><<<dim3(4, 4, 8), 256, 0, stream>>>(
      p_hi + 512, wqkt_hi, p_lo + 512, wqkt_lo, qk_hi, qk_lo, 512, 512, 512,
      512, 0, 4, /*sAq*/ -512, /*sAr*/ 0, /*sBq*/ 4 * HS, /*sBr*/ HS,
      /*sCq*/ 4 * HS, /*sCr*/ HS);
  gemm_nt<3, 3><<<dim3(4, 4, 4), 256, 0, stream>>>(
      qk_hi, qk_hi + 4 * HS, qk_lo, qk_lo + 4 * HS, sATT, nullptr, 512, 512,
      512, 512, 0, 4, 0, HS, 0, HS, 0, HS);
  softmax_krn_k<<<2048, 256, 0, stream>>>(sATT, krn32, krn16);

  // --- layer loop ---
  for (int l = 0; l < 4; ++l) {
    if (l > 0) {
      hipMemsetAsync(Lrow, 0, 2048L * 4, stream);
      // S8 = fp8(exp(f_k @ wte^T)), Lrow = fp32 row sums (M=2048, N=32000)
      gemm_nt<5, 1><<<dim3(16, 250, 1), 256, 0, stream>>>(
          fk16, wte16, nullptr, nullptr, S8, (short*)Lrow, 512, 512, 32000,
          512, 0, 1, 0, 0, 0, 0, 0, 0);
      // exw partials = S8 @ wteT8 (fp8 MFMA), split-K=10, bf16 slabs
      gemm8<<<dim3(16, 4, 10), 256, 0, stream>>>(S8, wteT8, exw_part, 32000,
                                                 32000, 512, 3200, 3200,
                                                 1048576L);
    }
    hipMemsetAsync(dl, 0, 4L * 2048 * 4, stream);
    vm_k<<<dim3(8, 8, 4), 256, 0, stream>>>(e32, exw_part, colmean, Lrow,
                                            krn32, (l == 0) ? 1 : 0,
                                            (l < 3) ? 1 : 0, vmT16, dl);
    flast_k<<<dim3(8, 4), 256, 0, stream>>>(dl, WoT, flast);
    if (l < 3) {
      // delta[b,h] = krn[h] @ Vm[b], scaled 1/(1+s), packed (b,s,h*512+e)
      gemm_nt<2, 1><<<dim3(4, 4, 16), 256, 0, stream>>>(
          krn16, vmT16, nullptr, nullptr, delta16, nullptr, 512, 512, 2048,
          512, 0, 4, 0, HS, HS, 0, 1048576L, 512);
      // fk partials = delta @ W_o^T, split-K=4, bf16 slabs
      gemm_nt<0, 1><<<dim3(16, 4, 4), 256, 0, stream>>>(
          delta16, wo16, nullptr, nullptr, fkpart, nullptr, 2048, 2048, 512,
          512, 512, 4, 0, 0, 0, 0, 0, 1048576L);
      fkupdate_k<<<1024, 256, 0, stream>>>(fkpart, fk32, fk16);
    }
  }

  // --- final LN + logits (pure fp32) ---
  ln_rows<<<4, 256, 0, stream>>>(flast, nullptr, nullptr, g_f, outln, nullptr,
                                 nullptr, 2);
  logits_k<<<500, 256, 0, stream>>>(outln, wte, out);
}